// Round 16
// baseline (291.970 us; speedup 1.0000x reference)
//
#include <hip/hip_runtime.h>
#include <hip/hip_bf16.h>

typedef unsigned short u16;   // bf16 bits
typedef __attribute__((ext_vector_type(8))) short short8v;   // 8 bf16 (4 VGPRs)
typedef __attribute__((ext_vector_type(4))) float f32x4;
typedef __attribute__((ext_vector_type(16))) float f32x16;
typedef union { short8v v; uint u[4]; } pack8;

__device__ __forceinline__ float bu2f(u16 u) {
    return __uint_as_float(((unsigned)u) << 16);
}
__device__ __forceinline__ u16 f2bu(float f) {   // RNE f32->bf16
    unsigned u = __float_as_uint(f);
    u += 0x7fffu + ((u >> 16) & 1u);
    return (u16)(u >> 16);
}
__device__ __forceinline__ uint pk2(float a, float b) {
    return (uint)f2bu(a) | ((uint)f2bu(b) << 16);
}

// ---------------------------------------------------------------------------
// K-repack: all weights -> MFMA-friendly bf16 layouts in ws.
//  w1p  [32][48]: k = kh*16 + kw*4 + c (zeros at kw==3 or c==3)  conv1 (v3)
//  s2wp [96][72]: rows 0-47 W_lin hi, 48-95 W_lin lo; k<48 valid stage2
//  w2p  [64][296]: k = tap*32 + ic                               conv2
//  w3p  [128][584]: k = tap*64 + ic                              conv3
// ---------------------------------------------------------------------------
__global__ __launch_bounds__(256) void k_repack(
    const float* __restrict__ Wlin, const float* __restrict__ c1w,
    const float* __restrict__ c2w, const float* __restrict__ c3w,
    u16* __restrict__ w1p, u16* __restrict__ s2wp,
    u16* __restrict__ w2p, u16* __restrict__ w3p)
{
    int i = blockIdx.x * 256 + threadIdx.x;
    if (i < 32 * 48) {
        int oc = i / 48, k = i - oc * 48;
        int kh = k >> 4, e = k & 15;
        int kw = e >> 2, c = e & 3;
        u16 v = 0;
        if (kw < 3 && c < 3)
            v = f2bu(c1w[((oc * 3 + c) * 3 + kh) * 3 + kw]);
        w1p[i] = v;
    }
    if (i < 96 * 72) {
        int r = i / 72, k = i - r * 72;
        u16 v = 0;
        if (k < 48) {
            int o = r % 48;
            float w = Wlin[o * 48 + k];
            u16 hi = f2bu(w);
            v = (r < 48) ? hi : f2bu(w - bu2f(hi));
        }
        s2wp[i] = v;
    }
    if (i < 64 * 288) {
        int oc = i / 288, r = i - oc * 288;
        int tap = r >> 5, ic = r & 31;
        w2p[oc * 296 + r] = f2bu(c2w[(oc * 32 + ic) * 9 + tap]);
    }
    if (i < 128 * 576) {
        int oc = i / 576, r = i - oc * 576;
        int tap = r >> 6, ic = r & 63;
        w3p[oc * 584 + r] = f2bu(c3w[(oc * 64 + ic) * 9 + tap]);
    }
}

// ---------------------------------------------------------------------------
// K-img v3: stage2 -> conv1 -> conv2 -> conv3, one WG per image.
// LDS cut 67.5 -> 51.0 KB to unlock 3 WG/CU (r15: VGPR 88 allows 3 waves/SIMD,
// LDS was the binder):
//  - image stored c-padded [34][34][4] (no E/O dual copy; conv1 A-frags are
//    two aligned ds_read_b64; K-layout kh*16+kw*4+c, pads hit zero weights)
//  - stage2 B-frags read from global (L2-broadcast), no S2W tile
//  - pool-before-bias+relu epilogues (bit-exact, ~5 fewer VALU/output)
// LDS map (u16): IMG4 [0,4624) | SCR [4624,11024): XB(stage2)/IN3(conv2 out)
//              | W1L [11024,12560) | IN2 [12560,25520).  Total 51.0 KB.
// ---------------------------------------------------------------------------
#define IMG4  0
#define SCR   4624
#define IN3   4624
#define W1L   11024
#define IN2   12560
#define LDS_N 25520

__global__ __launch_bounds__(256) void k_img(
    const float* __restrict__ x, const u16* __restrict__ s2wp,
    const u16* __restrict__ w1p, const float* __restrict__ c1b,
    const int* __restrict__ stage,
    const u16* __restrict__ w2p, const float* __restrict__ c2b,
    const u16* __restrict__ w3p, const float* __restrict__ c3b,
    u16* __restrict__ o3)
{
    __shared__ __align__(16) u16 lds[LDS_N];
    const int b = blockIdx.x, t = threadIdx.x;
    const int wv = t >> 6, lane = t & 63, lr = lane & 15, q = lane >> 4;
    uint* z32 = (uint*)lds;

    // ---- P0: zero IMG4 (full: c=3 plane + halo) + IN2 halo; load conv1 W ----
    for (int i = t; i < 2312; i += 256) z32[i] = 0u;
    for (int i = t; i < 1360; i += 256) {            // in2 halo: 68 cells x 20 dw
        int cell = i / 20, d = i - cell * 20;
        int h, w;
        if (cell < 18)      { h = 0;  w = cell; }
        else if (cell < 36) { h = 17; w = cell - 18; }
        else { int k = cell - 36; h = 1 + (k >> 1); w = (k & 1) * 17; }
        z32[6280 + (h * 18 + w) * 20 + d] = 0u;      // IN2/2 = 6280
    }
    for (int i = t; i < 192; i += 256)
        *(short8v*)(&lds[W1L + i * 8]) = *(const short8v*)(&w1p[i * 8]);

    const int sv = stage[0];
    if (sv == 2) {
        {   // build xb in SCR: thread t -> block n = t>>2, row ir = t&3
            const int n = t >> 2, ir = t & 3;
            const float* xp = x + (size_t)b * 3072 + (((n >> 3) * 4 + ir) * 96 + (n & 7) * 12);
            const float4 va = ((const float4*)xp)[0];
            const float4 vb = ((const float4*)xp)[1];
            const float4 vc = ((const float4*)xp)[2];
            uint* dst = (uint*)&lds[SCR + n * 72 + ir * 12];
            dst[0] = pk2(va.x, va.y); dst[1] = pk2(va.z, va.w);
            dst[2] = pk2(vb.x, vb.y); dst[3] = pk2(vb.z, vb.w);
            dst[4] = pk2(vc.x, vc.y); dst[5] = pk2(vc.z, vc.w);
            if (ir < 2) {
                uint* z2 = (uint*)&lds[SCR + n * 72 + 48 + ir * 8];
                z2[0] = 0u; z2[1] = 0u; z2[2] = 0u; z2[3] = 0u;
            }
        }
        // stage2 B-frags straight from global (L2-broadcast), issued pre-barrier
        short8v bh0[3], bh1[3], bl0[3], bl1[3];
        #pragma unroll
        for (int nf = 0; nf < 3; ++nf) {
            bh0[nf] = *(const short8v*)(&s2wp[(nf * 16 + lr) * 72 + q * 8]);
            bh1[nf] = *(const short8v*)(&s2wp[(nf * 16 + lr) * 72 + 32 + q * 8]);
            bl0[nf] = *(const short8v*)(&s2wp[(48 + nf * 16 + lr) * 72 + q * 8]);
            bl1[nf] = *(const short8v*)(&s2wp[(48 + nf * 16 + lr) * 72 + 32 + q * 8]);
        }
        __syncthreads();
        short8v a0 = *(const short8v*)&lds[SCR + (wv * 16 + lr) * 72 + q * 8];
        short8v a1 = *(const short8v*)&lds[SCR + (wv * 16 + lr) * 72 + 32 + q * 8];
        f32x4 y[3];
        #pragma unroll
        for (int nf = 0; nf < 3; ++nf) {
            y[nf] = (f32x4){0.f, 0.f, 0.f, 0.f};
            y[nf] = __builtin_amdgcn_mfma_f32_16x16x32_bf16(a0, bh0[nf], y[nf], 0, 0, 0);
            y[nf] = __builtin_amdgcn_mfma_f32_16x16x32_bf16(a1, bh1[nf], y[nf], 0, 0, 0);
            y[nf] = __builtin_amdgcn_mfma_f32_16x16x32_bf16(a0, bl0[nf], y[nf], 0, 0, 0);
            y[nf] = __builtin_amdgcn_mfma_f32_16x16x32_bf16(a1, bl1[nf], y[nf], 0, 0, 0);
        }
        // scatter y -> IMG4 interior (c 0..2; c=3 plane + halo stay zero)
        #pragma unroll
        for (int nf = 0; nf < 3; ++nf)
            #pragma unroll
            for (int r = 0; r < 4; ++r) {
                int n2 = wv * 16 + q * 4 + r;
                int o  = nf * 16 + lr;
                int ir = o / 12, rm = o - ir * 12;
                int jc = rm / 3, c = rm - jc * 3;
                int hh = (n2 >> 3) * 4 + ir, ww = (n2 & 7) * 4 + jc;
                lds[IMG4 + ((hh + 1) * 34 + (ww + 1)) * 4 + c] = f2bu(y[nf][r]);
            }
    } else {
        if (t < 4) z32[2312 + t] = 0u;     // conv1 over-read window (SCR head)
        __syncthreads();
        for (int e = t; e < 3072; e += 256) {
            int hh = e / 96, rm = e - hh * 96;
            int ww = rm / 3, c = rm - ww * 3;
            lds[IMG4 + ((hh + 1) * 34 + (ww + 1)) * 4 + c] = f2bu(x[(size_t)b * 3072 + e]);
        }
    }
    __syncthreads();     // IMG4 complete

    // ---- P2: conv1 via 32x32x16 MFMA -> IN2; zero IN3 halo (SCR, XB dead) ----
    for (int i = t; i < 1152; i += 256) {            // in3 halo: 36 cells x 32 dw
        int cell = i >> 5, d = i & 31;
        int pos;
        if (cell < 10)      pos = cell;
        else if (cell < 20) pos = 90 + (cell - 10);
        else { int k = cell - 20; pos = (1 + (k >> 1)) * 10 + (k & 1) * 9; }
        z32[2312 + pos * 32 + d] = 0u;               // IN3/2 = 2312
    }
    {
        const int oc32 = lane & 31, hi = lane >> 5;
        short8v wb[3];
        #pragma unroll
        for (int s = 0; s < 3; ++s)
            wb[s] = *(const short8v*)&lds[W1L + oc32 * 48 + s * 16 + hi * 8];
        const float bias1 = c1b[oc32];

        #pragma unroll
        for (int chk = 0; chk < 4; ++chk) {          // chunk = 2 h-rows
            f32x16 acc0, acc1;
            #pragma unroll
            for (int i = 0; i < 16; ++i) { acc0[i] = 0.f; acc1[i] = 0.f; }
            #pragma unroll
            for (int s = 0; s < 3; ++s) {
                #pragma unroll
                for (int f = 0; f < 2; ++f) {
                    const int h = wv * 8 + chk * 2 + f;
                    const int a4 = ((h + s) * 34 + oc32 + hi * 2) * 4;
                    pack8 pk;
                    *(unsigned long long*)&pk.u[0] = *(const unsigned long long*)(&lds[IMG4 + a4]);
                    *(unsigned long long*)&pk.u[2] = *(const unsigned long long*)(&lds[IMG4 + a4 + 4]);
                    if (f == 0) acc0 = __builtin_amdgcn_mfma_f32_32x32x16_bf16(pk.v, wb[s], acc0, 0, 0, 0);
                    else        acc1 = __builtin_amdgcn_mfma_f32_32x32x16_bf16(pk.v, wb[s], acc1, 0, 0, 0);
                }
            }
            const int hq = wv * 4 + chk;
            #pragma unroll
            for (int g = 0; g < 4; ++g) {
                #pragma unroll
                for (int pp = 0; pp < 2; ++pp) {
                    const int i0 = 4 * g + 2 * pp;
                    float m0 = fmaxf(acc0[i0], acc0[i0 + 1]);
                    float m1 = fmaxf(acc1[i0], acc1[i0 + 1]);
                    float v = fmaxf(fmaxf(m0, m1) + bias1, 0.f);
                    const int wq = 4 * g + 2 * hi + pp;
                    lds[IN2 + ((hq + 1) * 18 + (wq + 1)) * 40 + oc32] = f2bu(v);
                }
            }
        }
    }
    __syncthreads();     // IN2 complete, IN3 halo zeroed

    // ---- P3: conv2: B depth-2 global ring, A from IN2 ----
    {
        const u16* wb2 = w2p + (size_t)lr * 296 + q * 8;
        f32x4 acc[4][4];
        #pragma unroll
        for (int m = 0; m < 4; ++m)
            #pragma unroll
            for (int n = 0; n < 4; ++n) acc[m][n] = (f32x4){0.f, 0.f, 0.f, 0.f};

        short8v bfr[3][4];
        #pragma unroll
        for (int n = 0; n < 4; ++n) {
            bfr[0][n] = *(const short8v*)(wb2 + n * 4736 + 0);
            bfr[1][n] = *(const short8v*)(wb2 + n * 4736 + 32);
        }
        #pragma unroll
        for (int s = 0; s < 9; ++s) {
            if (s + 2 < 9) {
                #pragma unroll
                for (int n = 0; n < 4; ++n)
                    bfr[(s + 2) % 3][n] = *(const short8v*)(wb2 + n * 4736 + (s + 2) * 32);
            }
            const int kh = s / 3, kw = s - kh * 3;
            short8v af[4];
            #pragma unroll
            for (int m = 0; m < 4; ++m)
                af[m] = *(const short8v*)(&lds[IN2 + ((wv * 4 + m + kh) * 18 + lr + kw) * 40 + q * 8]);
            __builtin_amdgcn_s_setprio(1);
            #pragma unroll
            for (int m = 0; m < 4; ++m)
                #pragma unroll
                for (int n = 0; n < 4; ++n)
                    acc[m][n] = __builtin_amdgcn_mfma_f32_16x16x32_bf16(af[m], bfr[s % 3][n], acc[m][n], 0, 0, 0);
            __builtin_amdgcn_s_setprio(0);
        }
        // epilogue: pool -> +bias -> relu -> IN3 (swizzled)
        #pragma unroll
        for (int n = 0; n < 4; ++n) {
            float bias = c2b[n * 16 + lr];
            #pragma unroll
            for (int mp = 0; mp < 2; ++mp) {
                #pragma unroll
                for (int p = 0; p < 2; ++p) {
                    float m0 = fmaxf(acc[2 * mp][n][2 * p], acc[2 * mp][n][2 * p + 1]);
                    float m1 = fmaxf(acc[2 * mp + 1][n][2 * p], acc[2 * mp + 1][n][2 * p + 1]);
                    float v = fmaxf(fmaxf(m0, m1) + bias, 0.f);
                    int hq = wv * 2 + mp, wq = 2 * q + p;
                    int posW = (hq + 1) * 10 + (wq + 1);
                    int oc = n * 16 + lr;
                    lds[IN3 + posW * 64 + (oc ^ ((posW & 7) << 3))] = f2bu(v);
                }
            }
        }
    }
    __syncthreads();     // IN3 complete

    // ---- P4: conv3: wave wv -> oc block wv*32, B depth-2 ring ----
    {
        const int ocb = wv * 32;
        const int hA = lr >> 3, wA = lr & 7;
        const u16* wb3 = w3p + (size_t)(ocb + lr) * 584 + q * 8;

        f32x4 acc3[4][2];
        #pragma unroll
        for (int m = 0; m < 4; ++m)
            #pragma unroll
            for (int n = 0; n < 2; ++n) acc3[m][n] = (f32x4){0.f, 0.f, 0.f, 0.f};

        short8v br[3][2];
        #pragma unroll
        for (int n = 0; n < 2; ++n) {
            br[0][n] = *(const short8v*)(wb3 + n * 9344 + 0);
            br[1][n] = *(const short8v*)(wb3 + n * 9344 + 32);
        }
        #pragma unroll
        for (int s = 0; s < 18; ++s) {
            if (s + 2 < 18) {
                const int off2 = ((s + 2) >> 1) * 64 + ((s + 2) & 1) * 32;
                #pragma unroll
                for (int n = 0; n < 2; ++n)
                    br[(s + 2) % 3][n] = *(const short8v*)(wb3 + n * 9344 + off2);
            }
            const int tap = s >> 1, half = s & 1;
            const int kh = tap / 3, kw = tap - kh * 3;
            short8v a3[4];
            #pragma unroll
            for (int m = 0; m < 4; ++m) {
                int posR = (m * 2 + hA + kh) * 10 + wA + kw;
                int sl = (half * 32 + q * 8) ^ ((posR & 7) << 3);
                a3[m] = *(const short8v*)(&lds[IN3 + posR * 64 + sl]);
            }
            __builtin_amdgcn_s_setprio(1);
            #pragma unroll
            for (int m = 0; m < 4; ++m)
                #pragma unroll
                for (int n = 0; n < 2; ++n)
                    acc3[m][n] = __builtin_amdgcn_mfma_f32_16x16x32_bf16(a3[m], br[s % 3][n], acc3[m][n], 0, 0, 0);
            __builtin_amdgcn_s_setprio(0);
        }
        #pragma unroll
        for (int n = 0; n < 2; ++n) {
            float bias = c3b[ocb + n * 16 + lr];
            #pragma unroll
            for (int m = 0; m < 4; ++m) {
                #pragma unroll
                for (int p = 0; p < 2; ++p) {
                    float mm = fmaxf(acc3[m][n][2 * p], acc3[m][n][2 * p + 1]);
                    float v2 = fmaxf(mm, __shfl_xor(mm, 32));
                    float v = fmaxf(v2 + bias, 0.f);
                    if (lane < 32) {
                        int wq = (q & 1) * 2 + p;
                        o3[(size_t)b * 2048 + (m * 4 + wq) * 128 + ocb + n * 16 + lr] = f2bu(v);
                    }
                }
            }
        }
    }
}

// ---------------------------------------------------------------------------
// K5: fc (2048->10, NCHW flatten) + log_softmax. One wave/image (unchanged).
// ---------------------------------------------------------------------------
__global__ __launch_bounds__(256) void k_fc(
    const u16* __restrict__ o3, const float* __restrict__ fw,
    const float* __restrict__ fb, float* __restrict__ out)
{
    const int b = blockIdx.x * 4 + (threadIdx.x >> 6);
    const int lane = threadIdx.x & 63;
    const u16* xp = o3 + (size_t)b * 2048;
    float xr[32];
    #pragma unroll
    for (int i = 0; i < 32; ++i) {
        int kk = lane + i * 64;
        int c = kk >> 4, h = (kk >> 2) & 3, w = kk & 3;
        xr[i] = bu2f(xp[h * 512 + w * 128 + c]);
    }
    float lg[10];
    #pragma unroll
    for (int o = 0; o < 10; ++o) {
        const float* wr = fw + (size_t)o * 2048;
        float s = 0.f;
        #pragma unroll
        for (int i = 0; i < 32; ++i) s += xr[i] * wr[lane + i * 64];
        #pragma unroll
        for (int d = 32; d > 0; d >>= 1) s += __shfl_xor(s, d);
        lg[o] = s + fb[o];
    }
    float m = lg[0];
    #pragma unroll
    for (int o = 1; o < 10; ++o) m = fmaxf(m, lg[o]);
    float den = 0.f;
    #pragma unroll
    for (int o = 0; o < 10; ++o) den += expf(lg[o] - m);
    float lse = logf(den);
    if (lane < 10) {
        float v = lg[0];
        #pragma unroll
        for (int o = 1; o < 10; ++o) v = (lane == o) ? lg[o] : v;
        out[(size_t)b * 10 + lane] = v - m - lse;
    }
}

extern "C" void kernel_launch(void* const* d_in, const int* in_sizes, int n_in,
                              void* d_out, int out_size, void* d_ws, size_t ws_size,
                              hipStream_t stream)
{
    const float* x    = (const float*)d_in[0];
    const float* Wlin = (const float*)d_in[1];
    const float* c1w  = (const float*)d_in[2];
    const float* c1b  = (const float*)d_in[3];
    const float* c2w  = (const float*)d_in[4];
    const float* c2b  = (const float*)d_in[5];
    const float* c3w  = (const float*)d_in[6];
    const float* c3b  = (const float*)d_in[7];
    const float* fw   = (const float*)d_in[8];
    const float* fb   = (const float*)d_in[9];
    const int* stage  = (const int*)d_in[10];
    float* out = (float*)d_out;

    const int B = in_sizes[0] / 3072;      // 8192

    // ws: o3 [0, B*4096 B) ; weights after.
    char* ws = (char*)d_ws;
    u16* o3   = (u16*)ws;
    char* WB  = ws + (size_t)B * 4096;
    u16* w1p  = (u16*)(WB);
    u16* s2wp = (u16*)(WB + 4608);
    u16* w2p  = (u16*)(WB + 18432);
    u16* w3p  = (u16*)(WB + 56320);

    k_repack<<<288, 256, 0, stream>>>(Wlin, c1w, c2w, c3w, w1p, s2wp, w2p, w3p);
    k_img   <<<B, 256, 0, stream>>>(x, s2wp, w1p, c1b, stage, w2p, c2b, w3p, c3b, o3);
    k_fc    <<<B / 4, 256, 0, stream>>>(o3, fw, fb, out);
}

// Round 17
// 258.427 us; speedup vs baseline: 1.1298x; 1.1298x over previous
//
#include <hip/hip_runtime.h>
#include <hip/hip_bf16.h>

typedef unsigned short u16;   // bf16 bits
typedef __attribute__((ext_vector_type(8))) short short8v;   // 8 bf16 (4 VGPRs)
typedef __attribute__((ext_vector_type(4))) float f32x4;
typedef __attribute__((ext_vector_type(16))) float f32x16;
typedef union { short8v v; uint u[4]; } pack8;

__device__ __forceinline__ float bu2f(u16 u) {
    return __uint_as_float(((unsigned)u) << 16);
}
__device__ __forceinline__ u16 f2bu(float f) {   // RNE f32->bf16
    unsigned u = __float_as_uint(f);
    u += 0x7fffu + ((u >> 16) & 1u);
    return (u16)(u >> 16);
}
__device__ __forceinline__ uint pk2(float a, float b) {
    return (uint)f2bu(a) | ((uint)f2bu(b) << 16);
}

// ---------------------------------------------------------------------------
// K-repack: all weights -> MFMA-friendly bf16 layouts in ws.
//  w1p  [32][48]: k = kh*16 + kw*4 + c (zeros at kw==3 or c==3)  conv1
//  s2wp [96][72]: rows 0-47 W_lin hi, 48-95 W_lin lo; k<48 valid stage2
//  w2p  [64][296]: k = tap*32 + ic                               conv2
//  w3p  [128][584]: k = tap*64 + ic                              conv3
// ---------------------------------------------------------------------------
__global__ __launch_bounds__(256) void k_repack(
    const float* __restrict__ Wlin, const float* __restrict__ c1w,
    const float* __restrict__ c2w, const float* __restrict__ c3w,
    u16* __restrict__ w1p, u16* __restrict__ s2wp,
    u16* __restrict__ w2p, u16* __restrict__ w3p)
{
    int i = blockIdx.x * 256 + threadIdx.x;
    if (i < 32 * 48) {
        int oc = i / 48, k = i - oc * 48;
        int kh = k >> 4, e = k & 15;
        int kw = e >> 2, c = e & 3;
        u16 v = 0;
        if (kw < 3 && c < 3)
            v = f2bu(c1w[((oc * 3 + c) * 3 + kh) * 3 + kw]);
        w1p[i] = v;
    }
    if (i < 96 * 72) {
        int r = i / 72, k = i - r * 72;
        u16 v = 0;
        if (k < 48) {
            int o = r % 48;
            float w = Wlin[o * 48 + k];
            u16 hi = f2bu(w);
            v = (r < 48) ? hi : f2bu(w - bu2f(hi));
        }
        s2wp[i] = v;
    }
    if (i < 64 * 288) {
        int oc = i / 288, r = i - oc * 288;
        int tap = r >> 5, ic = r & 31;
        w2p[oc * 296 + r] = f2bu(c2w[(oc * 32 + ic) * 9 + tap]);
    }
    if (i < 128 * 576) {
        int oc = i / 576, r = i - oc * 576;
        int tap = r >> 6, ic = r & 63;
        w3p[oc * 584 + r] = f2bu(c3w[(oc * 64 + ic) * 9 + tap]);
    }
}

// ---------------------------------------------------------------------------
// K-img v4: stage2 -> conv1 -> conv2 -> conv3, one WG per image.
// v4 = v3 + __launch_bounds__(256,3). r16 evidence: at VGPR 92 + 64 acc the
// allocator lands in a 256-reg slot -> 2 waves/SIMD even though LDS (51.0 KB)
// now fits 3 WG/CU. The (256,3) cap (~170 regs/wave) fits the ~150-reg peak
// demand (conv2 phase) -- r11 proved 3 waves/SIMD + small spill wins at this
// exact phase structure. (r7's (256,3) disaster was demand ~230 >> cap.)
// LDS map (u16): IMG4 [0,4624) | SCR/IN3 [4624,11024) | W1L [11024,12560)
//              | IN2 [12560,25520).  Total 51.0 KB.
// ---------------------------------------------------------------------------
#define IMG4  0
#define SCR   4624
#define IN3   4624
#define W1L   11024
#define IN2   12560
#define LDS_N 25520

__global__ __launch_bounds__(256, 3) void k_img(
    const float* __restrict__ x, const u16* __restrict__ s2wp,
    const u16* __restrict__ w1p, const float* __restrict__ c1b,
    const int* __restrict__ stage,
    const u16* __restrict__ w2p, const float* __restrict__ c2b,
    const u16* __restrict__ w3p, const float* __restrict__ c3b,
    u16* __restrict__ o3)
{
    __shared__ __align__(16) u16 lds[LDS_N];
    const int b = blockIdx.x, t = threadIdx.x;
    const int wv = t >> 6, lane = t & 63, lr = lane & 15, q = lane >> 4;
    uint* z32 = (uint*)lds;

    // ---- P0: zero IMG4 (full: c=3 plane + halo) + IN2 halo; load conv1 W ----
    for (int i = t; i < 2312; i += 256) z32[i] = 0u;
    for (int i = t; i < 1360; i += 256) {            // in2 halo: 68 cells x 20 dw
        int cell = i / 20, d = i - cell * 20;
        int h, w;
        if (cell < 18)      { h = 0;  w = cell; }
        else if (cell < 36) { h = 17; w = cell - 18; }
        else { int k = cell - 36; h = 1 + (k >> 1); w = (k & 1) * 17; }
        z32[6280 + (h * 18 + w) * 20 + d] = 0u;      // IN2/2 = 6280
    }
    for (int i = t; i < 192; i += 256)
        *(short8v*)(&lds[W1L + i * 8]) = *(const short8v*)(&w1p[i * 8]);

    const int sv = stage[0];
    if (sv == 2) {
        {   // build xb in SCR: thread t -> block n = t>>2, row ir = t&3
            const int n = t >> 2, ir = t & 3;
            const float* xp = x + (size_t)b * 3072 + (((n >> 3) * 4 + ir) * 96 + (n & 7) * 12);
            const float4 va = ((const float4*)xp)[0];
            const float4 vb = ((const float4*)xp)[1];
            const float4 vc = ((const float4*)xp)[2];
            uint* dst = (uint*)&lds[SCR + n * 72 + ir * 12];
            dst[0] = pk2(va.x, va.y); dst[1] = pk2(va.z, va.w);
            dst[2] = pk2(vb.x, vb.y); dst[3] = pk2(vb.z, vb.w);
            dst[4] = pk2(vc.x, vc.y); dst[5] = pk2(vc.z, vc.w);
            if (ir < 2) {
                uint* z2 = (uint*)&lds[SCR + n * 72 + 48 + ir * 8];
                z2[0] = 0u; z2[1] = 0u; z2[2] = 0u; z2[3] = 0u;
            }
        }
        // stage2 B-frags straight from global (L2-broadcast), issued pre-barrier
        short8v bh0[3], bh1[3], bl0[3], bl1[3];
        #pragma unroll
        for (int nf = 0; nf < 3; ++nf) {
            bh0[nf] = *(const short8v*)(&s2wp[(nf * 16 + lr) * 72 + q * 8]);
            bh1[nf] = *(const short8v*)(&s2wp[(nf * 16 + lr) * 72 + 32 + q * 8]);
            bl0[nf] = *(const short8v*)(&s2wp[(48 + nf * 16 + lr) * 72 + q * 8]);
            bl1[nf] = *(const short8v*)(&s2wp[(48 + nf * 16 + lr) * 72 + 32 + q * 8]);
        }
        __syncthreads();
        short8v a0 = *(const short8v*)&lds[SCR + (wv * 16 + lr) * 72 + q * 8];
        short8v a1 = *(const short8v*)&lds[SCR + (wv * 16 + lr) * 72 + 32 + q * 8];
        f32x4 y[3];
        #pragma unroll
        for (int nf = 0; nf < 3; ++nf) {
            y[nf] = (f32x4){0.f, 0.f, 0.f, 0.f};
            y[nf] = __builtin_amdgcn_mfma_f32_16x16x32_bf16(a0, bh0[nf], y[nf], 0, 0, 0);
            y[nf] = __builtin_amdgcn_mfma_f32_16x16x32_bf16(a1, bh1[nf], y[nf], 0, 0, 0);
            y[nf] = __builtin_amdgcn_mfma_f32_16x16x32_bf16(a0, bl0[nf], y[nf], 0, 0, 0);
            y[nf] = __builtin_amdgcn_mfma_f32_16x16x32_bf16(a1, bl1[nf], y[nf], 0, 0, 0);
        }
        // scatter y -> IMG4 interior (c 0..2; c=3 plane + halo stay zero)
        #pragma unroll
        for (int nf = 0; nf < 3; ++nf)
            #pragma unroll
            for (int r = 0; r < 4; ++r) {
                int n2 = wv * 16 + q * 4 + r;
                int o  = nf * 16 + lr;
                int ir = o / 12, rm = o - ir * 12;
                int jc = rm / 3, c = rm - jc * 3;
                int hh = (n2 >> 3) * 4 + ir, ww = (n2 & 7) * 4 + jc;
                lds[IMG4 + ((hh + 1) * 34 + (ww + 1)) * 4 + c] = f2bu(y[nf][r]);
            }
    } else {
        if (t < 4) z32[2312 + t] = 0u;     // conv1 over-read window (SCR head)
        __syncthreads();
        for (int e = t; e < 3072; e += 256) {
            int hh = e / 96, rm = e - hh * 96;
            int ww = rm / 3, c = rm - ww * 3;
            lds[IMG4 + ((hh + 1) * 34 + (ww + 1)) * 4 + c] = f2bu(x[(size_t)b * 3072 + e]);
        }
    }
    __syncthreads();     // IMG4 complete

    // ---- P2: conv1 via 32x32x16 MFMA -> IN2; zero IN3 halo (SCR, XB dead) ----
    for (int i = t; i < 1152; i += 256) {            // in3 halo: 36 cells x 32 dw
        int cell = i >> 5, d = i & 31;
        int pos;
        if (cell < 10)      pos = cell;
        else if (cell < 20) pos = 90 + (cell - 10);
        else { int k = cell - 20; pos = (1 + (k >> 1)) * 10 + (k & 1) * 9; }
        z32[2312 + pos * 32 + d] = 0u;               // IN3/2 = 2312
    }
    {
        const int oc32 = lane & 31, hi = lane >> 5;
        short8v wb[3];
        #pragma unroll
        for (int s = 0; s < 3; ++s)
            wb[s] = *(const short8v*)&lds[W1L + oc32 * 48 + s * 16 + hi * 8];
        const float bias1 = c1b[oc32];

        #pragma unroll
        for (int chk = 0; chk < 4; ++chk) {          // chunk = 2 h-rows
            f32x16 acc0, acc1;
            #pragma unroll
            for (int i = 0; i < 16; ++i) { acc0[i] = 0.f; acc1[i] = 0.f; }
            #pragma unroll
            for (int s = 0; s < 3; ++s) {
                #pragma unroll
                for (int f = 0; f < 2; ++f) {
                    const int h = wv * 8 + chk * 2 + f;
                    const int a4 = ((h + s) * 34 + oc32 + hi * 2) * 4;
                    pack8 pk;
                    *(unsigned long long*)&pk.u[0] = *(const unsigned long long*)(&lds[IMG4 + a4]);
                    *(unsigned long long*)&pk.u[2] = *(const unsigned long long*)(&lds[IMG4 + a4 + 4]);
                    if (f == 0) acc0 = __builtin_amdgcn_mfma_f32_32x32x16_bf16(pk.v, wb[s], acc0, 0, 0, 0);
                    else        acc1 = __builtin_amdgcn_mfma_f32_32x32x16_bf16(pk.v, wb[s], acc1, 0, 0, 0);
                }
            }
            const int hq = wv * 4 + chk;
            #pragma unroll
            for (int g = 0; g < 4; ++g) {
                #pragma unroll
                for (int pp = 0; pp < 2; ++pp) {
                    const int i0 = 4 * g + 2 * pp;
                    float m0 = fmaxf(acc0[i0], acc0[i0 + 1]);
                    float m1 = fmaxf(acc1[i0], acc1[i0 + 1]);
                    float v = fmaxf(fmaxf(m0, m1) + bias1, 0.f);
                    const int wq = 4 * g + 2 * hi + pp;
                    lds[IN2 + ((hq + 1) * 18 + (wq + 1)) * 40 + oc32] = f2bu(v);
                }
            }
        }
    }
    __syncthreads();     // IN2 complete, IN3 halo zeroed

    // ---- P3: conv2: B depth-2 global ring, A from IN2 ----
    {
        const u16* wb2 = w2p + (size_t)lr * 296 + q * 8;
        f32x4 acc[4][4];
        #pragma unroll
        for (int m = 0; m < 4; ++m)
            #pragma unroll
            for (int n = 0; n < 4; ++n) acc[m][n] = (f32x4){0.f, 0.f, 0.f, 0.f};

        short8v bfr[3][4];
        #pragma unroll
        for (int n = 0; n < 4; ++n) {
            bfr[0][n] = *(const short8v*)(wb2 + n * 4736 + 0);
            bfr[1][n] = *(const short8v*)(wb2 + n * 4736 + 32);
        }
        #pragma unroll
        for (int s = 0; s < 9; ++s) {
            if (s + 2 < 9) {
                #pragma unroll
                for (int n = 0; n < 4; ++n)
                    bfr[(s + 2) % 3][n] = *(const short8v*)(wb2 + n * 4736 + (s + 2) * 32);
            }
            const int kh = s / 3, kw = s - kh * 3;
            short8v af[4];
            #pragma unroll
            for (int m = 0; m < 4; ++m)
                af[m] = *(const short8v*)(&lds[IN2 + ((wv * 4 + m + kh) * 18 + lr + kw) * 40 + q * 8]);
            __builtin_amdgcn_s_setprio(1);
            #pragma unroll
            for (int m = 0; m < 4; ++m)
                #pragma unroll
                for (int n = 0; n < 4; ++n)
                    acc[m][n] = __builtin_amdgcn_mfma_f32_16x16x32_bf16(af[m], bfr[s % 3][n], acc[m][n], 0, 0, 0);
            __builtin_amdgcn_s_setprio(0);
        }
        // epilogue: pool -> +bias -> relu -> IN3 (swizzled)
        #pragma unroll
        for (int n = 0; n < 4; ++n) {
            float bias = c2b[n * 16 + lr];
            #pragma unroll
            for (int mp = 0; mp < 2; ++mp) {
                #pragma unroll
                for (int p = 0; p < 2; ++p) {
                    float m0 = fmaxf(acc[2 * mp][n][2 * p], acc[2 * mp][n][2 * p + 1]);
                    float m1 = fmaxf(acc[2 * mp + 1][n][2 * p], acc[2 * mp + 1][n][2 * p + 1]);
                    float v = fmaxf(fmaxf(m0, m1) + bias, 0.f);
                    int hq = wv * 2 + mp, wq = 2 * q + p;
                    int posW = (hq + 1) * 10 + (wq + 1);
                    int oc = n * 16 + lr;
                    lds[IN3 + posW * 64 + (oc ^ ((posW & 7) << 3))] = f2bu(v);
                }
            }
        }
    }
    __syncthreads();     // IN3 complete

    // ---- P4: conv3: wave wv -> oc block wv*32, B depth-2 ring ----
    {
        const int ocb = wv * 32;
        const int hA = lr >> 3, wA = lr & 7;
        const u16* wb3 = w3p + (size_t)(ocb + lr) * 584 + q * 8;

        f32x4 acc3[4][2];
        #pragma unroll
        for (int m = 0; m < 4; ++m)
            #pragma unroll
            for (int n = 0; n < 2; ++n) acc3[m][n] = (f32x4){0.f, 0.f, 0.f, 0.f};

        short8v br[3][2];
        #pragma unroll
        for (int n = 0; n < 2; ++n) {
            br[0][n] = *(const short8v*)(wb3 + n * 9344 + 0);
            br[1][n] = *(const short8v*)(wb3 + n * 9344 + 32);
        }
        #pragma unroll
        for (int s = 0; s < 18; ++s) {
            if (s + 2 < 18) {
                const int off2 = ((s + 2) >> 1) * 64 + ((s + 2) & 1) * 32;
                #pragma unroll
                for (int n = 0; n < 2; ++n)
                    br[(s + 2) % 3][n] = *(const short8v*)(wb3 + n * 9344 + off2);
            }
            const int tap = s >> 1, half = s & 1;
            const int kh = tap / 3, kw = tap - kh * 3;
            short8v a3[4];
            #pragma unroll
            for (int m = 0; m < 4; ++m) {
                int posR = (m * 2 + hA + kh) * 10 + wA + kw;
                int sl = (half * 32 + q * 8) ^ ((posR & 7) << 3);
                a3[m] = *(const short8v*)(&lds[IN3 + posR * 64 + sl]);
            }
            __builtin_amdgcn_s_setprio(1);
            #pragma unroll
            for (int m = 0; m < 4; ++m)
                #pragma unroll
                for (int n = 0; n < 2; ++n)
                    acc3[m][n] = __builtin_amdgcn_mfma_f32_16x16x32_bf16(a3[m], br[s % 3][n], acc3[m][n], 0, 0, 0);
            __builtin_amdgcn_s_setprio(0);
        }
        #pragma unroll
        for (int n = 0; n < 2; ++n) {
            float bias = c3b[ocb + n * 16 + lr];
            #pragma unroll
            for (int m = 0; m < 4; ++m) {
                #pragma unroll
                for (int p = 0; p < 2; ++p) {
                    float mm = fmaxf(acc3[m][n][2 * p], acc3[m][n][2 * p + 1]);
                    float v2 = fmaxf(mm, __shfl_xor(mm, 32));
                    float v = fmaxf(v2 + bias, 0.f);
                    if (lane < 32) {
                        int wq = (q & 1) * 2 + p;
                        o3[(size_t)b * 2048 + (m * 4 + wq) * 128 + ocb + n * 16 + lr] = f2bu(v);
                    }
                }
            }
        }
    }
}

// ---------------------------------------------------------------------------
// K5: fc (2048->10, NCHW flatten) + log_softmax. One wave/image (unchanged).
// ---------------------------------------------------------------------------
__global__ __launch_bounds__(256) void k_fc(
    const u16* __restrict__ o3, const float* __restrict__ fw,
    const float* __restrict__ fb, float* __restrict__ out)
{
    const int b = blockIdx.x * 4 + (threadIdx.x >> 6);
    const int lane = threadIdx.x & 63;
    const u16* xp = o3 + (size_t)b * 2048;
    float xr[32];
    #pragma unroll
    for (int i = 0; i < 32; ++i) {
        int kk = lane + i * 64;
        int c = kk >> 4, h = (kk >> 2) & 3, w = kk & 3;
        xr[i] = bu2f(xp[h * 512 + w * 128 + c]);
    }
    float lg[10];
    #pragma unroll
    for (int o = 0; o < 10; ++o) {
        const float* wr = fw + (size_t)o * 2048;
        float s = 0.f;
        #pragma unroll
        for (int i = 0; i < 32; ++i) s += xr[i] * wr[lane + i * 64];
        #pragma unroll
        for (int d = 32; d > 0; d >>= 1) s += __shfl_xor(s, d);
        lg[o] = s + fb[o];
    }
    float m = lg[0];
    #pragma unroll
    for (int o = 1; o < 10; ++o) m = fmaxf(m, lg[o]);
    float den = 0.f;
    #pragma unroll
    for (int o = 0; o < 10; ++o) den += expf(lg[o] - m);
    float lse = logf(den);
    if (lane < 10) {
        float v = lg[0];
        #pragma unroll
        for (int o = 1; o < 10; ++o) v = (lane == o) ? lg[o] : v;
        out[(size_t)b * 10 + lane] = v - m - lse;
    }
}

extern "C" void kernel_launch(void* const* d_in, const int* in_sizes, int n_in,
                              void* d_out, int out_size, void* d_ws, size_t ws_size,
                              hipStream_t stream)
{
    const float* x    = (const float*)d_in[0];
    const float* Wlin = (const float*)d_in[1];
    const float* c1w  = (const float*)d_in[2];
    const float* c1b  = (const float*)d_in[3];
    const float* c2w  = (const float*)d_in[4];
    const float* c2b  = (const float*)d_in[5];
    const float* c3w  = (const float*)d_in[6];
    const float* c3b  = (const float*)d_in[7];
    const float* fw   = (const float*)d_in[8];
    const float* fb   = (const float*)d_in[9];
    const int* stage  = (const int*)d_in[10];
    float* out = (float*)d_out;

    const int B = in_sizes[0] / 3072;      // 8192

    // ws: o3 [0, B*4096 B) ; weights after.
    char* ws = (char*)d_ws;
    u16* o3   = (u16*)ws;
    char* WB  = ws + (size_t)B * 4096;
    u16* w1p  = (u16*)(WB);
    u16* s2wp = (u16*)(WB + 4608);
    u16* w2p  = (u16*)(WB + 18432);
    u16* w3p  = (u16*)(WB + 56320);

    k_repack<<<288, 256, 0, stream>>>(Wlin, c1w, c2w, c3w, w1p, s2wp, w2p, w3p);
    k_img   <<<B, 256, 0, stream>>>(x, s2wp, w1p, c1b, stage, w2p, c2b, w3p, c3b, o3);
    k_fc    <<<B / 4, 256, 0, stream>>>(o3, fw, fb, out);
}

// Round 18
// 256.617 us; speedup vs baseline: 1.1378x; 1.0071x over previous
//
#include <hip/hip_runtime.h>
#include <hip/hip_bf16.h>

typedef unsigned short u16;   // bf16 bits
typedef __attribute__((ext_vector_type(8))) short short8v;   // 8 bf16 (4 VGPRs)
typedef __attribute__((ext_vector_type(4))) float f32x4;
typedef __attribute__((ext_vector_type(16))) float f32x16;
typedef union { short8v v; uint u[4]; } pack8;

__device__ __forceinline__ float bu2f(u16 u) {
    return __uint_as_float(((unsigned)u) << 16);
}
__device__ __forceinline__ u16 f2bu(float f) {   // RNE f32->bf16
    unsigned u = __float_as_uint(f);
    u += 0x7fffu + ((u >> 16) & 1u);
    return (u16)(u >> 16);
}
__device__ __forceinline__ uint pk2(float a, float b) {
    return (uint)f2bu(a) | ((uint)f2bu(b) << 16);
}

// ---------------------------------------------------------------------------
// K-repack: all weights -> MFMA-friendly bf16 layouts in ws (unchanged).
//  w1p  [32][48]: k = kh*16 + kw*4 + c (zeros at kw==3 or c==3)  conv1
//  s2wp [96][72]: rows 0-47 W_lin hi, 48-95 W_lin lo; k<48 valid stage2
//  w2p  [64][296]: k = tap*32 + ic                               conv2
//  w3p  [128][584]: k = tap*64 + ic                              conv3
// ---------------------------------------------------------------------------
__global__ __launch_bounds__(256) void k_repack(
    const float* __restrict__ Wlin, const float* __restrict__ c1w,
    const float* __restrict__ c2w, const float* __restrict__ c3w,
    u16* __restrict__ w1p, u16* __restrict__ s2wp,
    u16* __restrict__ w2p, u16* __restrict__ w3p)
{
    int i = blockIdx.x * 256 + threadIdx.x;
    if (i < 32 * 48) {
        int oc = i / 48, k = i - oc * 48;
        int kh = k >> 4, e = k & 15;
        int kw = e >> 2, c = e & 3;
        u16 v = 0;
        if (kw < 3 && c < 3)
            v = f2bu(c1w[((oc * 3 + c) * 3 + kh) * 3 + kw]);
        w1p[i] = v;
    }
    if (i < 96 * 72) {
        int r = i / 72, k = i - r * 72;
        u16 v = 0;
        if (k < 48) {
            int o = r % 48;
            float w = Wlin[o * 48 + k];
            u16 hi = f2bu(w);
            v = (r < 48) ? hi : f2bu(w - bu2f(hi));
        }
        s2wp[i] = v;
    }
    if (i < 64 * 288) {
        int oc = i / 288, r = i - oc * 288;
        int tap = r >> 5, ic = r & 31;
        w2p[oc * 296 + r] = f2bu(c2w[(oc * 32 + ic) * 9 + tap]);
    }
    if (i < 128 * 576) {
        int oc = i / 576, r = i - oc * 576;
        int tap = r >> 6, ic = r & 63;
        w3p[oc * 584 + r] = f2bu(c3w[(oc * 64 + ic) * 9 + tap]);
    }
}

// ---------------------------------------------------------------------------
// K-img v5: stage2 -> conv1 -> conv2 -> conv3, one WG per image.
// v5 unlocks 4 waves/SIMD (r17 ladder: 2w=290us, 3w=246us):
//  - LDS 51.0 -> 37.8 KB: W1L dropped (conv1 W = 3 per-lane global loads,
//    issued P0, live +12 regs through P1); IN3 overlays dead IMG4/XB
//    (halo zeroed at P3 start, after IMG4 dies).
//  - conv2 split into two N=32 halves: peak live regs 64acc+48ring ->
//    32acc+24ring+16af ~= 72 (+addr ~100 arch) < 128 = 512/4 cap.
//  - __launch_bounds__(256,4).
// LDS map (u16): IMG4 [0,4624) | XB [4624,9232) (stage2, dead after P1)
//              | IN3 [0,6400) (P3 epi -> P4) | IN2 [6400,19360).
// ---------------------------------------------------------------------------
#define IMG4  0
#define XB    4624
#define IN3   0
#define IN2   6400
#define LDS_N 19360

__global__ __launch_bounds__(256, 4) void k_img(
    const float* __restrict__ x, const u16* __restrict__ s2wp,
    const u16* __restrict__ w1p, const float* __restrict__ c1b,
    const int* __restrict__ stage,
    const u16* __restrict__ w2p, const float* __restrict__ c2b,
    const u16* __restrict__ w3p, const float* __restrict__ c3b,
    u16* __restrict__ o3)
{
    __shared__ __align__(16) u16 lds[LDS_N];
    const int b = blockIdx.x, t = threadIdx.x;
    const int wv = t >> 6, lane = t & 63, lr = lane & 15, q = lane >> 4;
    const int oc32 = lane & 31, hi = lane >> 5;
    uint* z32 = (uint*)lds;

    // ---- P0: zero IMG4 (full, incl. c=3 plane + halo); conv1 W -> regs ----
    for (int i = t; i < 2312; i += 256) z32[i] = 0u;
    short8v wb1[3];
    #pragma unroll
    for (int s = 0; s < 3; ++s)
        wb1[s] = *(const short8v*)(&w1p[oc32 * 48 + s * 16 + hi * 8]);

    const int sv = stage[0];
    if (sv == 2) {
        {   // build xb in XB: thread t -> block n = t>>2, row ir = t&3
            const int n = t >> 2, ir = t & 3;
            const float* xp = x + (size_t)b * 3072 + (((n >> 3) * 4 + ir) * 96 + (n & 7) * 12);
            const float4 va = ((const float4*)xp)[0];
            const float4 vb = ((const float4*)xp)[1];
            const float4 vc = ((const float4*)xp)[2];
            uint* dst = (uint*)&lds[XB + n * 72 + ir * 12];
            dst[0] = pk2(va.x, va.y); dst[1] = pk2(va.z, va.w);
            dst[2] = pk2(vb.x, vb.y); dst[3] = pk2(vb.z, vb.w);
            dst[4] = pk2(vc.x, vc.y); dst[5] = pk2(vc.z, vc.w);
            if (ir < 2) {
                uint* z2 = (uint*)&lds[XB + n * 72 + 48 + ir * 8];
                z2[0] = 0u; z2[1] = 0u; z2[2] = 0u; z2[3] = 0u;
            }
        }
        // stage2 B-frags straight from global (L2-broadcast), issued pre-barrier
        short8v bh0[3], bh1[3], bl0[3], bl1[3];
        #pragma unroll
        for (int nf = 0; nf < 3; ++nf) {
            bh0[nf] = *(const short8v*)(&s2wp[(nf * 16 + lr) * 72 + q * 8]);
            bh1[nf] = *(const short8v*)(&s2wp[(nf * 16 + lr) * 72 + 32 + q * 8]);
            bl0[nf] = *(const short8v*)(&s2wp[(48 + nf * 16 + lr) * 72 + q * 8]);
            bl1[nf] = *(const short8v*)(&s2wp[(48 + nf * 16 + lr) * 72 + 32 + q * 8]);
        }
        __syncthreads();
        short8v a0 = *(const short8v*)&lds[XB + (wv * 16 + lr) * 72 + q * 8];
        short8v a1 = *(const short8v*)&lds[XB + (wv * 16 + lr) * 72 + 32 + q * 8];
        f32x4 y[3];
        #pragma unroll
        for (int nf = 0; nf < 3; ++nf) {
            y[nf] = (f32x4){0.f, 0.f, 0.f, 0.f};
            y[nf] = __builtin_amdgcn_mfma_f32_16x16x32_bf16(a0, bh0[nf], y[nf], 0, 0, 0);
            y[nf] = __builtin_amdgcn_mfma_f32_16x16x32_bf16(a1, bh1[nf], y[nf], 0, 0, 0);
            y[nf] = __builtin_amdgcn_mfma_f32_16x16x32_bf16(a0, bl0[nf], y[nf], 0, 0, 0);
            y[nf] = __builtin_amdgcn_mfma_f32_16x16x32_bf16(a1, bl1[nf], y[nf], 0, 0, 0);
        }
        __syncthreads();
        // scatter y -> IMG4 interior (c 0..2; c=3 plane + halo stay zero).
        // Over-read window at IMG4 end lands in XB head: those elements feed
        // k=12..15 (kw==3) slots whose conv1 weights are zero -> safe.
        #pragma unroll
        for (int nf = 0; nf < 3; ++nf)
            #pragma unroll
            for (int r = 0; r < 4; ++r) {
                int n2 = wv * 16 + q * 4 + r;
                int o  = nf * 16 + lr;
                int ir = o / 12, rm = o - ir * 12;
                int jc = rm / 3, c = rm - jc * 3;
                int hh = (n2 >> 3) * 4 + ir, ww = (n2 & 7) * 4 + jc;
                lds[IMG4 + ((hh + 1) * 34 + (ww + 1)) * 4 + c] = f2bu(y[nf][r]);
            }
    } else {
        if (t < 4) z32[2312 + t] = 0u;     // conv1 over-read window (XB head)
        __syncthreads();
        for (int e = t; e < 3072; e += 256) {
            int hh = e / 96, rm = e - hh * 96;
            int ww = rm / 3, c = rm - ww * 3;
            lds[IMG4 + ((hh + 1) * 34 + (ww + 1)) * 4 + c] = f2bu(x[(size_t)b * 3072 + e]);
        }
    }
    __syncthreads();     // IMG4 complete; XB dead after this phase

    // ---- P2: conv1 via 32x32x16 MFMA -> IN2; zero IN2 halo (XB dead) ----
    for (int i = t; i < 1360; i += 256) {            // in2 halo: 68 cells x 20 dw
        int cell = i / 20, d = i - cell * 20;
        int h, w;
        if (cell < 18)      { h = 0;  w = cell; }
        else if (cell < 36) { h = 17; w = cell - 18; }
        else { int k = cell - 36; h = 1 + (k >> 1); w = (k & 1) * 17; }
        z32[3200 + (h * 18 + w) * 20 + d] = 0u;      // IN2/2 = 3200
    }
    {
        const float bias1 = c1b[oc32];
        #pragma unroll
        for (int chk = 0; chk < 4; ++chk) {          // chunk = 2 h-rows
            f32x16 acc0, acc1;
            #pragma unroll
            for (int i = 0; i < 16; ++i) { acc0[i] = 0.f; acc1[i] = 0.f; }
            #pragma unroll
            for (int s = 0; s < 3; ++s) {
                #pragma unroll
                for (int f = 0; f < 2; ++f) {
                    const int h = wv * 8 + chk * 2 + f;
                    const int a4 = ((h + s) * 34 + oc32 + hi * 2) * 4;
                    pack8 pk;
                    *(unsigned long long*)&pk.u[0] = *(const unsigned long long*)(&lds[IMG4 + a4]);
                    *(unsigned long long*)&pk.u[2] = *(const unsigned long long*)(&lds[IMG4 + a4 + 4]);
                    if (f == 0) acc0 = __builtin_amdgcn_mfma_f32_32x32x16_bf16(pk.v, wb1[s], acc0, 0, 0, 0);
                    else        acc1 = __builtin_amdgcn_mfma_f32_32x32x16_bf16(pk.v, wb1[s], acc1, 0, 0, 0);
                }
            }
            const int hq = wv * 4 + chk;
            #pragma unroll
            for (int g = 0; g < 4; ++g) {
                #pragma unroll
                for (int pp = 0; pp < 2; ++pp) {
                    const int i0 = 4 * g + 2 * pp;
                    float m0 = fmaxf(acc0[i0], acc0[i0 + 1]);
                    float m1 = fmaxf(acc1[i0], acc1[i0 + 1]);
                    float v = fmaxf(fmaxf(m0, m1) + bias1, 0.f);
                    const int wq = 4 * g + 2 * hi + pp;
                    lds[IN2 + ((hq + 1) * 18 + (wq + 1)) * 40 + oc32] = f2bu(v);
                }
            }
        }
    }
    __syncthreads();     // IN2 complete; IMG4 dead after this phase

    // ---- P3: conv2 in two N=32 halves (acc 32 regs); IN3 halo zero first ----
    for (int i = t; i < 1152; i += 256) {            // in3 halo: 36 cells x 32 dw
        int cell = i >> 5, d = i & 31;
        int pos;
        if (cell < 10)      pos = cell;
        else if (cell < 20) pos = 90 + (cell - 10);
        else { int k = cell - 20; pos = (1 + (k >> 1)) * 10 + (k & 1) * 9; }
        z32[pos * 32 + d] = 0u;                      // IN3/2 = 0
    }
    #pragma unroll
    for (int nh = 0; nh < 2; ++nh) {
        const u16* wb2 = w2p + (size_t)(nh * 32 + lr) * 296 + q * 8;
        f32x4 acc[4][2];
        #pragma unroll
        for (int m = 0; m < 4; ++m)
            #pragma unroll
            for (int n = 0; n < 2; ++n) acc[m][n] = (f32x4){0.f, 0.f, 0.f, 0.f};

        short8v bfr[3][2];
        #pragma unroll
        for (int n = 0; n < 2; ++n) {
            bfr[0][n] = *(const short8v*)(wb2 + n * 4736 + 0);
            bfr[1][n] = *(const short8v*)(wb2 + n * 4736 + 32);
        }
        #pragma unroll
        for (int s = 0; s < 9; ++s) {
            if (s + 2 < 9) {
                #pragma unroll
                for (int n = 0; n < 2; ++n)
                    bfr[(s + 2) % 3][n] = *(const short8v*)(wb2 + n * 4736 + (s + 2) * 32);
            }
            const int kh = s / 3, kw = s - kh * 3;
            short8v af[4];
            #pragma unroll
            for (int m = 0; m < 4; ++m)
                af[m] = *(const short8v*)(&lds[IN2 + ((wv * 4 + m + kh) * 18 + lr + kw) * 40 + q * 8]);
            __builtin_amdgcn_s_setprio(1);
            #pragma unroll
            for (int m = 0; m < 4; ++m)
                #pragma unroll
                for (int n = 0; n < 2; ++n)
                    acc[m][n] = __builtin_amdgcn_mfma_f32_16x16x32_bf16(af[m], bfr[s % 3][n], acc[m][n], 0, 0, 0);
            __builtin_amdgcn_s_setprio(0);
        }
        // epilogue: pool -> +bias -> relu -> IN3 (swizzled)
        #pragma unroll
        for (int n = 0; n < 2; ++n) {
            float bias = c2b[nh * 32 + n * 16 + lr];
            #pragma unroll
            for (int mp = 0; mp < 2; ++mp) {
                #pragma unroll
                for (int p = 0; p < 2; ++p) {
                    float m0 = fmaxf(acc[2 * mp][n][2 * p], acc[2 * mp][n][2 * p + 1]);
                    float m1 = fmaxf(acc[2 * mp + 1][n][2 * p], acc[2 * mp + 1][n][2 * p + 1]);
                    float v = fmaxf(fmaxf(m0, m1) + bias, 0.f);
                    int hq = wv * 2 + mp, wq = 2 * q + p;
                    int posW = (hq + 1) * 10 + (wq + 1);
                    int oc = nh * 32 + n * 16 + lr;
                    lds[IN3 + posW * 64 + (oc ^ ((posW & 7) << 3))] = f2bu(v);
                }
            }
        }
    }
    __syncthreads();     // IN3 complete

    // ---- P4: conv3: wave wv -> oc block wv*32, B depth-2 ring ----
    {
        const int ocb = wv * 32;
        const int hA = lr >> 3, wA = lr & 7;
        const u16* wb3 = w3p + (size_t)(ocb + lr) * 584 + q * 8;

        f32x4 acc3[4][2];
        #pragma unroll
        for (int m = 0; m < 4; ++m)
            #pragma unroll
            for (int n = 0; n < 2; ++n) acc3[m][n] = (f32x4){0.f, 0.f, 0.f, 0.f};

        short8v br[3][2];
        #pragma unroll
        for (int n = 0; n < 2; ++n) {
            br[0][n] = *(const short8v*)(wb3 + n * 9344 + 0);
            br[1][n] = *(const short8v*)(wb3 + n * 9344 + 32);
        }
        #pragma unroll
        for (int s = 0; s < 18; ++s) {
            if (s + 2 < 18) {
                const int off2 = ((s + 2) >> 1) * 64 + ((s + 2) & 1) * 32;
                #pragma unroll
                for (int n = 0; n < 2; ++n)
                    br[(s + 2) % 3][n] = *(const short8v*)(wb3 + n * 9344 + off2);
            }
            const int tap = s >> 1, half = s & 1;
            const int kh = tap / 3, kw = tap - kh * 3;
            short8v a3[4];
            #pragma unroll
            for (int m = 0; m < 4; ++m) {
                int posR = (m * 2 + hA + kh) * 10 + wA + kw;
                int sl = (half * 32 + q * 8) ^ ((posR & 7) << 3);
                a3[m] = *(const short8v*)(&lds[IN3 + posR * 64 + sl]);
            }
            __builtin_amdgcn_s_setprio(1);
            #pragma unroll
            for (int m = 0; m < 4; ++m)
                #pragma unroll
                for (int n = 0; n < 2; ++n)
                    acc3[m][n] = __builtin_amdgcn_mfma_f32_16x16x32_bf16(a3[m], br[s % 3][n], acc3[m][n], 0, 0, 0);
            __builtin_amdgcn_s_setprio(0);
        }
        #pragma unroll
        for (int n = 0; n < 2; ++n) {
            float bias = c3b[ocb + n * 16 + lr];
            #pragma unroll
            for (int m = 0; m < 4; ++m) {
                #pragma unroll
                for (int p = 0; p < 2; ++p) {
                    float mm = fmaxf(acc3[m][n][2 * p], acc3[m][n][2 * p + 1]);
                    float v2 = fmaxf(mm, __shfl_xor(mm, 32));
                    float v = fmaxf(v2 + bias, 0.f);
                    if (lane < 32) {
                        int wq = (q & 1) * 2 + p;
                        o3[(size_t)b * 2048 + (m * 4 + wq) * 128 + ocb + n * 16 + lr] = f2bu(v);
                    }
                }
            }
        }
    }
}

// ---------------------------------------------------------------------------
// K5: fc (2048->10, NCHW flatten) + log_softmax. One wave/image (unchanged).
// ---------------------------------------------------------------------------
__global__ __launch_bounds__(256) void k_fc(
    const u16* __restrict__ o3, const float* __restrict__ fw,
    const float* __restrict__ fb, float* __restrict__ out)
{
    const int b = blockIdx.x * 4 + (threadIdx.x >> 6);
    const int lane = threadIdx.x & 63;
    const u16* xp = o3 + (size_t)b * 2048;
    float xr[32];
    #pragma unroll
    for (int i = 0; i < 32; ++i) {
        int kk = lane + i * 64;
        int c = kk >> 4, h = (kk >> 2) & 3, w = kk & 3;
        xr[i] = bu2f(xp[h * 512 + w * 128 + c]);
    }
    float lg[10];
    #pragma unroll
    for (int o = 0; o < 10; ++o) {
        const float* wr = fw + (size_t)o * 2048;
        float s = 0.f;
        #pragma unroll
        for (int i = 0; i < 32; ++i) s += xr[i] * wr[lane + i * 64];
        #pragma unroll
        for (int d = 32; d > 0; d >>= 1) s += __shfl_xor(s, d);
        lg[o] = s + fb[o];
    }
    float m = lg[0];
    #pragma unroll
    for (int o = 1; o < 10; ++o) m = fmaxf(m, lg[o]);
    float den = 0.f;
    #pragma unroll
    for (int o = 0; o < 10; ++o) den += expf(lg[o] - m);
    float lse = logf(den);
    if (lane < 10) {
        float v = lg[0];
        #pragma unroll
        for (int o = 1; o < 10; ++o) v = (lane == o) ? lg[o] : v;
        out[(size_t)b * 10 + lane] = v - m - lse;
    }
}

extern "C" void kernel_launch(void* const* d_in, const int* in_sizes, int n_in,
                              void* d_out, int out_size, void* d_ws, size_t ws_size,
                              hipStream_t stream)
{
    const float* x    = (const float*)d_in[0];
    const float* Wlin = (const float*)d_in[1];
    const float* c1w  = (const float*)d_in[2];
    const float* c1b  = (const float*)d_in[3];
    const float* c2w  = (const float*)d_in[4];
    const float* c2b  = (const float*)d_in[5];
    const float* c3w  = (const float*)d_in[6];
    const float* c3b  = (const float*)d_in[7];
    const float* fw   = (const float*)d_in[8];
    const float* fb   = (const float*)d_in[9];
    const int* stage  = (const int*)d_in[10];
    float* out = (float*)d_out;

    const int B = in_sizes[0] / 3072;      // 8192

    // ws: o3 [0, B*4096 B) ; weights after.
    char* ws = (char*)d_ws;
    u16* o3   = (u16*)ws;
    char* WB  = ws + (size_t)B * 4096;
    u16* w1p  = (u16*)(WB);
    u16* s2wp = (u16*)(WB + 4608);
    u16* w2p  = (u16*)(WB + 18432);
    u16* w3p  = (u16*)(WB + 56320);

    k_repack<<<288, 256, 0, stream>>>(Wlin, c1w, c2w, c3w, w1p, s2wp, w2p, w3p);
    k_img   <<<B, 256, 0, stream>>>(x, s2wp, w1p, c1b, stage, w2p, c2b, w3p, c3b, o3);
    k_fc    <<<B / 4, 256, 0, stream>>>(o3, fw, fb, out);
}

// Round 19
// 238.724 us; speedup vs baseline: 1.2230x; 1.0750x over previous
//
#include <hip/hip_runtime.h>
#include <hip/hip_bf16.h>

typedef unsigned short u16;   // bf16 bits
typedef __attribute__((ext_vector_type(8))) short short8v;   // 8 bf16 (4 VGPRs)
typedef __attribute__((ext_vector_type(4))) float f32x4;
typedef __attribute__((ext_vector_type(16))) float f32x16;
typedef union { short8v v; uint u[4]; } pack8;

__device__ __forceinline__ float bu2f(u16 u) {
    return __uint_as_float(((unsigned)u) << 16);
}
__device__ __forceinline__ u16 f2bu(float f) {   // RNE f32->bf16
    unsigned u = __float_as_uint(f);
    u += 0x7fffu + ((u >> 16) & 1u);
    return (u16)(u >> 16);
}
__device__ __forceinline__ uint pk2(float a, float b) {
    return (uint)f2bu(a) | ((uint)f2bu(b) << 16);
}

// ---------------------------------------------------------------------------
// K-repack: weights -> MFMA-friendly bf16 layouts in ws.
//  w1p  [32][48]: k = kh*16 + kw*4 + c (zeros at kw==3 or c==3)  conv1
//  s2wp [96][72]: rows 0-47 W_lin hi, 48-95 W_lin lo; k<48 valid stage2
//  w2p  [64][296]: k = tap*32 + ic                               conv2
//  w3p  [128][584]: k = tap*64 + ic                              conv3
// ---------------------------------------------------------------------------
__global__ __launch_bounds__(256) void k_repack(
    const float* __restrict__ Wlin, const float* __restrict__ c1w,
    const float* __restrict__ c2w, const float* __restrict__ c3w,
    u16* __restrict__ w1p, u16* __restrict__ s2wp,
    u16* __restrict__ w2p, u16* __restrict__ w3p)
{
    int i = blockIdx.x * 256 + threadIdx.x;
    if (i < 32 * 48) {
        int oc = i / 48, k = i - oc * 48;
        int kh = k >> 4, e = k & 15;
        int kw = e >> 2, c = e & 3;
        u16 v = 0;
        if (kw < 3 && c < 3)
            v = f2bu(c1w[((oc * 3 + c) * 3 + kh) * 3 + kw]);
        w1p[i] = v;
    }
    if (i < 96 * 72) {
        int r = i / 72, k = i - r * 72;
        u16 v = 0;
        if (k < 48) {
            int o = r % 48;
            float w = Wlin[o * 48 + k];
            u16 hi = f2bu(w);
            v = (r < 48) ? hi : f2bu(w - bu2f(hi));
        }
        s2wp[i] = v;
    }
    if (i < 64 * 288) {
        int oc = i / 288, r = i - oc * 288;
        int tap = r >> 5, ic = r & 31;
        w2p[oc * 296 + r] = f2bu(c2w[(oc * 32 + ic) * 9 + tap]);
    }
    if (i < 128 * 576) {
        int oc = i / 576, r = i - oc * 576;
        int tap = r >> 6, ic = r & 63;
        w3p[oc * 584 + r] = f2bu(c3w[(oc * 64 + ic) * 9 + tap]);
    }
}

// ---------------------------------------------------------------------------
// K-img v6: stage2 -> conv1 -> conv2 -> conv3 -> fc+log_softmax, ONE kernel.
// v6 = v5 + P5 (fc head fused): P4 writes the pooled 2048-vector to LDS
// (XF, NCHW-flat k = oc*16 + h*4 + w) instead of o3 in HBM; P5 computes
// 10 logits in-WG (per-thread 8-elem partial dots, f32 fw via float4,
// shfl+LDS tree reduce, wave-0 softmax) and writes out directly.
// Removes k_fc launch + o3's 66 MB HBM round-trip.
// LDS map (u16): IMG4 [0,4624) | XB [4624,9232) (dead after P1)
//              | IN3 [0,6400) | IN2 [6400,19360) | XF [6400,8448) (P4->P5)
//              | red 40 f32 @ u16 8448.
// ---------------------------------------------------------------------------
#define IMG4  0
#define XB    4624
#define IN3   0
#define IN2   6400
#define XF    6400
#define LDS_N 19360

__global__ __launch_bounds__(256, 4) void k_img(
    const float* __restrict__ x, const u16* __restrict__ s2wp,
    const u16* __restrict__ w1p, const float* __restrict__ c1b,
    const int* __restrict__ stage,
    const u16* __restrict__ w2p, const float* __restrict__ c2b,
    const u16* __restrict__ w3p, const float* __restrict__ c3b,
    const float* __restrict__ fw, const float* __restrict__ fb,
    float* __restrict__ out)
{
    __shared__ __align__(16) u16 lds[LDS_N];
    const int b = blockIdx.x, t = threadIdx.x;
    const int wv = t >> 6, lane = t & 63, lr = lane & 15, q = lane >> 4;
    const int oc32 = lane & 31, hi = lane >> 5;
    uint* z32 = (uint*)lds;

    // ---- P0: zero IMG4 (full, incl. c=3 plane + halo); conv1 W -> regs ----
    for (int i = t; i < 2312; i += 256) z32[i] = 0u;
    short8v wb1[3];
    #pragma unroll
    for (int s = 0; s < 3; ++s)
        wb1[s] = *(const short8v*)(&w1p[oc32 * 48 + s * 16 + hi * 8]);

    const int sv = stage[0];
    if (sv == 2) {
        {   // build xb in XB: thread t -> block n = t>>2, row ir = t&3
            const int n = t >> 2, ir = t & 3;
            const float* xp = x + (size_t)b * 3072 + (((n >> 3) * 4 + ir) * 96 + (n & 7) * 12);
            const float4 va = ((const float4*)xp)[0];
            const float4 vb = ((const float4*)xp)[1];
            const float4 vc = ((const float4*)xp)[2];
            uint* dst = (uint*)&lds[XB + n * 72 + ir * 12];
            dst[0] = pk2(va.x, va.y); dst[1] = pk2(va.z, va.w);
            dst[2] = pk2(vb.x, vb.y); dst[3] = pk2(vb.z, vb.w);
            dst[4] = pk2(vc.x, vc.y); dst[5] = pk2(vc.z, vc.w);
            if (ir < 2) {
                uint* z2 = (uint*)&lds[XB + n * 72 + 48 + ir * 8];
                z2[0] = 0u; z2[1] = 0u; z2[2] = 0u; z2[3] = 0u;
            }
        }
        // stage2 B-frags straight from global (L2-broadcast), issued pre-barrier
        short8v bh0[3], bh1[3], bl0[3], bl1[3];
        #pragma unroll
        for (int nf = 0; nf < 3; ++nf) {
            bh0[nf] = *(const short8v*)(&s2wp[(nf * 16 + lr) * 72 + q * 8]);
            bh1[nf] = *(const short8v*)(&s2wp[(nf * 16 + lr) * 72 + 32 + q * 8]);
            bl0[nf] = *(const short8v*)(&s2wp[(48 + nf * 16 + lr) * 72 + q * 8]);
            bl1[nf] = *(const short8v*)(&s2wp[(48 + nf * 16 + lr) * 72 + 32 + q * 8]);
        }
        __syncthreads();
        short8v a0 = *(const short8v*)&lds[XB + (wv * 16 + lr) * 72 + q * 8];
        short8v a1 = *(const short8v*)&lds[XB + (wv * 16 + lr) * 72 + 32 + q * 8];
        f32x4 y[3];
        #pragma unroll
        for (int nf = 0; nf < 3; ++nf) {
            y[nf] = (f32x4){0.f, 0.f, 0.f, 0.f};
            y[nf] = __builtin_amdgcn_mfma_f32_16x16x32_bf16(a0, bh0[nf], y[nf], 0, 0, 0);
            y[nf] = __builtin_amdgcn_mfma_f32_16x16x32_bf16(a1, bh1[nf], y[nf], 0, 0, 0);
            y[nf] = __builtin_amdgcn_mfma_f32_16x16x32_bf16(a0, bl0[nf], y[nf], 0, 0, 0);
            y[nf] = __builtin_amdgcn_mfma_f32_16x16x32_bf16(a1, bl1[nf], y[nf], 0, 0, 0);
        }
        __syncthreads();
        // scatter y -> IMG4 interior (c 0..2; c=3 plane + halo stay zero).
        #pragma unroll
        for (int nf = 0; nf < 3; ++nf)
            #pragma unroll
            for (int r = 0; r < 4; ++r) {
                int n2 = wv * 16 + q * 4 + r;
                int o  = nf * 16 + lr;
                int ir = o / 12, rm = o - ir * 12;
                int jc = rm / 3, c = rm - jc * 3;
                int hh = (n2 >> 3) * 4 + ir, ww = (n2 & 7) * 4 + jc;
                lds[IMG4 + ((hh + 1) * 34 + (ww + 1)) * 4 + c] = f2bu(y[nf][r]);
            }
    } else {
        if (t < 4) z32[2312 + t] = 0u;     // conv1 over-read window (XB head)
        __syncthreads();
        for (int e = t; e < 3072; e += 256) {
            int hh = e / 96, rm = e - hh * 96;
            int ww = rm / 3, c = rm - ww * 3;
            lds[IMG4 + ((hh + 1) * 34 + (ww + 1)) * 4 + c] = f2bu(x[(size_t)b * 3072 + e]);
        }
    }
    __syncthreads();     // IMG4 complete; XB dead after this phase

    // ---- P2: conv1 via 32x32x16 MFMA -> IN2; zero IN2 halo (XB dead) ----
    for (int i = t; i < 1360; i += 256) {            // in2 halo: 68 cells x 20 dw
        int cell = i / 20, d = i - cell * 20;
        int h, w;
        if (cell < 18)      { h = 0;  w = cell; }
        else if (cell < 36) { h = 17; w = cell - 18; }
        else { int k = cell - 36; h = 1 + (k >> 1); w = (k & 1) * 17; }
        z32[3200 + (h * 18 + w) * 20 + d] = 0u;      // IN2/2 = 3200
    }
    {
        const float bias1 = c1b[oc32];
        #pragma unroll
        for (int chk = 0; chk < 4; ++chk) {          // chunk = 2 h-rows
            f32x16 acc0, acc1;
            #pragma unroll
            for (int i = 0; i < 16; ++i) { acc0[i] = 0.f; acc1[i] = 0.f; }
            #pragma unroll
            for (int s = 0; s < 3; ++s) {
                #pragma unroll
                for (int f = 0; f < 2; ++f) {
                    const int h = wv * 8 + chk * 2 + f;
                    const int a4 = ((h + s) * 34 + oc32 + hi * 2) * 4;
                    pack8 pk;
                    *(unsigned long long*)&pk.u[0] = *(const unsigned long long*)(&lds[IMG4 + a4]);
                    *(unsigned long long*)&pk.u[2] = *(const unsigned long long*)(&lds[IMG4 + a4 + 4]);
                    if (f == 0) acc0 = __builtin_amdgcn_mfma_f32_32x32x16_bf16(pk.v, wb1[s], acc0, 0, 0, 0);
                    else        acc1 = __builtin_amdgcn_mfma_f32_32x32x16_bf16(pk.v, wb1[s], acc1, 0, 0, 0);
                }
            }
            const int hq = wv * 4 + chk;
            #pragma unroll
            for (int g = 0; g < 4; ++g) {
                #pragma unroll
                for (int pp = 0; pp < 2; ++pp) {
                    const int i0 = 4 * g + 2 * pp;
                    float m0 = fmaxf(acc0[i0], acc0[i0 + 1]);
                    float m1 = fmaxf(acc1[i0], acc1[i0 + 1]);
                    float v = fmaxf(fmaxf(m0, m1) + bias1, 0.f);
                    const int wq = 4 * g + 2 * hi + pp;
                    lds[IN2 + ((hq + 1) * 18 + (wq + 1)) * 40 + oc32] = f2bu(v);
                }
            }
        }
    }
    __syncthreads();     // IN2 complete; IMG4 dead after this phase

    // ---- P3: conv2 in two N=32 halves; IN3 halo zero first ----
    for (int i = t; i < 1152; i += 256) {            // in3 halo: 36 cells x 32 dw
        int cell = i >> 5, d = i & 31;
        int pos;
        if (cell < 10)      pos = cell;
        else if (cell < 20) pos = 90 + (cell - 10);
        else { int k = cell - 20; pos = (1 + (k >> 1)) * 10 + (k & 1) * 9; }
        z32[pos * 32 + d] = 0u;                      // IN3/2 = 0
    }
    #pragma unroll
    for (int nh = 0; nh < 2; ++nh) {
        const u16* wb2 = w2p + (size_t)(nh * 32 + lr) * 296 + q * 8;
        f32x4 acc[4][2];
        #pragma unroll
        for (int m = 0; m < 4; ++m)
            #pragma unroll
            for (int n = 0; n < 2; ++n) acc[m][n] = (f32x4){0.f, 0.f, 0.f, 0.f};

        short8v bfr[3][2];
        #pragma unroll
        for (int n = 0; n < 2; ++n) {
            bfr[0][n] = *(const short8v*)(wb2 + n * 4736 + 0);
            bfr[1][n] = *(const short8v*)(wb2 + n * 4736 + 32);
        }
        #pragma unroll
        for (int s = 0; s < 9; ++s) {
            if (s + 2 < 9) {
                #pragma unroll
                for (int n = 0; n < 2; ++n)
                    bfr[(s + 2) % 3][n] = *(const short8v*)(wb2 + n * 4736 + (s + 2) * 32);
            }
            const int kh = s / 3, kw = s - kh * 3;
            short8v af[4];
            #pragma unroll
            for (int m = 0; m < 4; ++m)
                af[m] = *(const short8v*)(&lds[IN2 + ((wv * 4 + m + kh) * 18 + lr + kw) * 40 + q * 8]);
            __builtin_amdgcn_s_setprio(1);
            #pragma unroll
            for (int m = 0; m < 4; ++m)
                #pragma unroll
                for (int n = 0; n < 2; ++n)
                    acc[m][n] = __builtin_amdgcn_mfma_f32_16x16x32_bf16(af[m], bfr[s % 3][n], acc[m][n], 0, 0, 0);
            __builtin_amdgcn_s_setprio(0);
        }
        // epilogue: pool -> +bias -> relu -> IN3 (swizzled)
        #pragma unroll
        for (int n = 0; n < 2; ++n) {
            float bias = c2b[nh * 32 + n * 16 + lr];
            #pragma unroll
            for (int mp = 0; mp < 2; ++mp) {
                #pragma unroll
                for (int p = 0; p < 2; ++p) {
                    float m0 = fmaxf(acc[2 * mp][n][2 * p], acc[2 * mp][n][2 * p + 1]);
                    float m1 = fmaxf(acc[2 * mp + 1][n][2 * p], acc[2 * mp + 1][n][2 * p + 1]);
                    float v = fmaxf(fmaxf(m0, m1) + bias, 0.f);
                    int hq = wv * 2 + mp, wq = 2 * q + p;
                    int posW = (hq + 1) * 10 + (wq + 1);
                    int oc = nh * 32 + n * 16 + lr;
                    lds[IN3 + posW * 64 + (oc ^ ((posW & 7) << 3))] = f2bu(v);
                }
            }
        }
    }
    __syncthreads();     // IN3 complete; IN2 dead after this barrier

    // ---- P4: conv3: wave wv -> oc block wv*32; pooled out -> XF (LDS) ----
    {
        const int ocb = wv * 32;
        const int hA = lr >> 3, wA = lr & 7;
        const u16* wb3 = w3p + (size_t)(ocb + lr) * 584 + q * 8;

        f32x4 acc3[4][2];
        #pragma unroll
        for (int m = 0; m < 4; ++m)
            #pragma unroll
            for (int n = 0; n < 2; ++n) acc3[m][n] = (f32x4){0.f, 0.f, 0.f, 0.f};

        short8v br[3][2];
        #pragma unroll
        for (int n = 0; n < 2; ++n) {
            br[0][n] = *(const short8v*)(wb3 + n * 9344 + 0);
            br[1][n] = *(const short8v*)(wb3 + n * 9344 + 32);
        }
        #pragma unroll
        for (int s = 0; s < 18; ++s) {
            if (s + 2 < 18) {
                const int off2 = ((s + 2) >> 1) * 64 + ((s + 2) & 1) * 32;
                #pragma unroll
                for (int n = 0; n < 2; ++n)
                    br[(s + 2) % 3][n] = *(const short8v*)(wb3 + n * 9344 + off2);
            }
            const int tap = s >> 1, half = s & 1;
            const int kh = tap / 3, kw = tap - kh * 3;
            short8v a3[4];
            #pragma unroll
            for (int m = 0; m < 4; ++m) {
                int posR = (m * 2 + hA + kh) * 10 + wA + kw;
                int sl = (half * 32 + q * 8) ^ ((posR & 7) << 3);
                a3[m] = *(const short8v*)(&lds[IN3 + posR * 64 + sl]);
            }
            __builtin_amdgcn_s_setprio(1);
            #pragma unroll
            for (int m = 0; m < 4; ++m)
                #pragma unroll
                for (int n = 0; n < 2; ++n)
                    acc3[m][n] = __builtin_amdgcn_mfma_f32_16x16x32_bf16(a3[m], br[s % 3][n], acc3[m][n], 0, 0, 0);
            __builtin_amdgcn_s_setprio(0);
        }
        #pragma unroll
        for (int n = 0; n < 2; ++n) {
            float bias = c3b[ocb + n * 16 + lr];
            #pragma unroll
            for (int m = 0; m < 4; ++m) {
                #pragma unroll
                for (int p = 0; p < 2; ++p) {
                    float mm = fmaxf(acc3[m][n][2 * p], acc3[m][n][2 * p + 1]);
                    float v2 = fmaxf(mm, __shfl_xor(mm, 32));
                    float v = fmaxf(v2 + bias, 0.f);
                    if (lane < 32) {
                        int wq = (q & 1) * 2 + p;
                        // NCHW-flat k = oc*16 + h*4 + w ; h = m, w = wq
                        lds[XF + (ocb + n * 16 + lr) * 16 + m * 4 + wq] = f2bu(v);
                    }
                }
            }
        }
    }
    __syncthreads();     // XF complete

    // ---- P5: fc (2048->10) + log_softmax, in-WG ----
    {
        const short8v xv = *(const short8v*)(&lds[XF + t * 8]);
        float xr[8];
        #pragma unroll
        for (int i = 0; i < 8; ++i) xr[i] = bu2f(((const u16*)&xv)[i]);
        float part[10];
        #pragma unroll
        for (int o = 0; o < 10; ++o) {
            const float* wr = fw + (size_t)o * 2048 + t * 8;
            const float4 wa = ((const float4*)wr)[0];
            const float4 wb = ((const float4*)wr)[1];
            part[o] = xr[0] * wa.x + xr[1] * wa.y + xr[2] * wa.z + xr[3] * wa.w
                    + xr[4] * wb.x + xr[5] * wb.y + xr[6] * wb.z + xr[7] * wb.w;
        }
        #pragma unroll
        for (int o = 0; o < 10; ++o) {
            float s = part[o];
            #pragma unroll
            for (int d = 32; d > 0; d >>= 1) s += __shfl_xor(s, d);
            part[o] = s;
        }
        float* redf = (float*)&lds[XF + 2048];   // 40 floats (overlays dead IN2)
        if (lane == 0) {
            #pragma unroll
            for (int o = 0; o < 10; ++o) redf[wv * 10 + o] = part[o];
        }
        __syncthreads();
        if (wv == 0) {
            float lg = -1e30f;
            if (lane < 10)
                lg = redf[lane] + redf[10 + lane] + redf[20 + lane] + redf[30 + lane] + fb[lane];
            float mx = lg;
            #pragma unroll
            for (int d = 8; d > 0; d >>= 1) mx = fmaxf(mx, __shfl_xor(mx, d));
            float ex = (lane < 10) ? expf(lg - mx) : 0.f;
            float den = ex;
            #pragma unroll
            for (int d = 8; d > 0; d >>= 1) den += __shfl_xor(den, d);
            if (lane < 10)
                out[(size_t)b * 10 + lane] = lg - mx - logf(den);
        }
    }
}

extern "C" void kernel_launch(void* const* d_in, const int* in_sizes, int n_in,
                              void* d_out, int out_size, void* d_ws, size_t ws_size,
                              hipStream_t stream)
{
    const float* x    = (const float*)d_in[0];
    const float* Wlin = (const float*)d_in[1];
    const float* c1w  = (const float*)d_in[2];
    const float* c1b  = (const float*)d_in[3];
    const float* c2w  = (const float*)d_in[4];
    const float* c2b  = (const float*)d_in[5];
    const float* c3w  = (const float*)d_in[6];
    const float* c3b  = (const float*)d_in[7];
    const float* fw   = (const float*)d_in[8];
    const float* fb   = (const float*)d_in[9];
    const int* stage  = (const int*)d_in[10];
    float* out = (float*)d_out;

    const int B = in_sizes[0] / 3072;      // 8192

    // ws: weights only (o3 eliminated).
    char* ws = (char*)d_ws;
    u16* w1p  = (u16*)(ws);
    u16* s2wp = (u16*)(ws + 4608);
    u16* w2p  = (u16*)(ws + 18432);
    u16* w3p  = (u16*)(ws + 56320);

    k_repack<<<288, 256, 0, stream>>>(Wlin, c1w, c2w, c3w, w1p, s2wp, w2p, w3p);
    k_img   <<<B, 256, 0, stream>>>(x, s2wp, w1p, c1b, stage, w2p, c2b, w3p, c3b, fw, fb, out);
}

// Round 20
// 237.937 us; speedup vs baseline: 1.2271x; 1.0033x over previous
//
#include <hip/hip_runtime.h>
#include <hip/hip_bf16.h>

typedef unsigned short u16;   // bf16 bits
typedef __attribute__((ext_vector_type(8))) short short8v;   // 8 bf16 (4 VGPRs)
typedef __attribute__((ext_vector_type(4))) float f32x4;
typedef __attribute__((ext_vector_type(16))) float f32x16;
typedef union { short8v v; uint u[4]; } pack8;

__device__ __forceinline__ float bu2f(u16 u) {
    return __uint_as_float(((unsigned)u) << 16);
}
__device__ __forceinline__ u16 f2bu(float f) {   // RNE f32->bf16
    unsigned u = __float_as_uint(f);
    u += 0x7fffu + ((u >> 16) & 1u);
    return (u16)(u >> 16);
}
__device__ __forceinline__ uint pk2(float a, float b) {
    return (uint)f2bu(a) | ((uint)f2bu(b) << 16);
}

// ---------------------------------------------------------------------------
// K-repack: weights -> MFMA-friendly bf16 layouts in ws (unchanged).
//  w1p  [32][48]: k = kh*16 + kw*4 + c (zeros at kw==3 or c==3)  conv1
//  s2wp [96][72]: rows 0-47 W_lin hi, 48-95 W_lin lo; k<48 valid stage2
//  w2p  [64][296]: k = tap*32 + ic                               conv2
//  w3p  [128][584]: k = tap*64 + ic                              conv3
// ---------------------------------------------------------------------------
__global__ __launch_bounds__(256) void k_repack(
    const float* __restrict__ Wlin, const float* __restrict__ c1w,
    const float* __restrict__ c2w, const float* __restrict__ c3w,
    u16* __restrict__ w1p, u16* __restrict__ s2wp,
    u16* __restrict__ w2p, u16* __restrict__ w3p)
{
    int i = blockIdx.x * 256 + threadIdx.x;
    if (i < 32 * 48) {
        int oc = i / 48, k = i - oc * 48;
        int kh = k >> 4, e = k & 15;
        int kw = e >> 2, c = e & 3;
        u16 v = 0;
        if (kw < 3 && c < 3)
            v = f2bu(c1w[((oc * 3 + c) * 3 + kh) * 3 + kw]);
        w1p[i] = v;
    }
    if (i < 96 * 72) {
        int r = i / 72, k = i - r * 72;
        u16 v = 0;
        if (k < 48) {
            int o = r % 48;
            float w = Wlin[o * 48 + k];
            u16 hi = f2bu(w);
            v = (r < 48) ? hi : f2bu(w - bu2f(hi));
        }
        s2wp[i] = v;
    }
    if (i < 64 * 288) {
        int oc = i / 288, r = i - oc * 288;
        int tap = r >> 5, ic = r & 31;
        w2p[oc * 296 + r] = f2bu(c2w[(oc * 32 + ic) * 9 + tap]);
    }
    if (i < 128 * 576) {
        int oc = i / 576, r = i - oc * 576;
        int tap = r >> 6, ic = r & 63;
        w3p[oc * 584 + r] = f2bu(c3w[(oc * 64 + ic) * 9 + tap]);
    }
}

// ---------------------------------------------------------------------------
// K-img v7: stage2 -> conv1 -> conv2 -> conv3 -> fc+log_softmax, ONE kernel.
// v7 vs v6:
//  - XF stored f32 (removes one bf16 rounding in fc path; r19 absmax margin)
//  - IN2 stride 40 -> 36 u16 (72B rows: bank-start 18*lr mod 32, uniform
//    2-way on b128 = free)
//  - conv2's IN3 writes DEFERRED past a barrier (pooled vals in 16 regs), so
//    IN3 overlays IN2 head; peak LDS = P2's IMG4+IN2 = 16288 u16 = 32576 B
//    -> rounds to 32768 B -> 5 WG/CU (was 4). +1 barrier, covered by TLP.
// LDS map (u16): IMG4 [0,4624) | XB [4624,9232) (P1 only)
//   | IN2 [4624,16288) stride 36 (P2 write -> P3 read)
//   | IN3 [0,6400) (post-P3-barrier -> P4) | XF f32 @dw3200 [u16 6400,10496)
//   | red 40 f32 @dw5248.  Total 16288 u16 = 32576 B.
// ---------------------------------------------------------------------------
#define IMG4  0
#define XB    4624
#define IN3   0
#define IN2   4624
#define LDS_N 16288

__global__ __launch_bounds__(256, 4) void k_img(
    const float* __restrict__ x, const u16* __restrict__ s2wp,
    const u16* __restrict__ w1p, const float* __restrict__ c1b,
    const int* __restrict__ stage,
    const u16* __restrict__ w2p, const float* __restrict__ c2b,
    const u16* __restrict__ w3p, const float* __restrict__ c3b,
    const float* __restrict__ fw, const float* __restrict__ fb,
    float* __restrict__ out)
{
    __shared__ __align__(16) u16 lds[LDS_N];
    const int b = blockIdx.x, t = threadIdx.x;
    const int wv = t >> 6, lane = t & 63, lr = lane & 15, q = lane >> 4;
    const int oc32 = lane & 31, hi = lane >> 5;
    uint* z32 = (uint*)lds;

    // ---- P0: zero IMG4 (full, incl. c=3 plane + halo); conv1 W -> regs ----
    for (int i = t; i < 2312; i += 256) z32[i] = 0u;
    short8v wb1[3];
    #pragma unroll
    for (int s = 0; s < 3; ++s)
        wb1[s] = *(const short8v*)(&w1p[oc32 * 48 + s * 16 + hi * 8]);

    const int sv = stage[0];
    if (sv == 2) {
        {   // build xb in XB: thread t -> block n = t>>2, row ir = t&3
            const int n = t >> 2, ir = t & 3;
            const float* xp = x + (size_t)b * 3072 + (((n >> 3) * 4 + ir) * 96 + (n & 7) * 12);
            const float4 va = ((const float4*)xp)[0];
            const float4 vb = ((const float4*)xp)[1];
            const float4 vc = ((const float4*)xp)[2];
            uint* dst = (uint*)&lds[XB + n * 72 + ir * 12];
            dst[0] = pk2(va.x, va.y); dst[1] = pk2(va.z, va.w);
            dst[2] = pk2(vb.x, vb.y); dst[3] = pk2(vb.z, vb.w);
            dst[4] = pk2(vc.x, vc.y); dst[5] = pk2(vc.z, vc.w);
            if (ir < 2) {
                uint* z2 = (uint*)&lds[XB + n * 72 + 48 + ir * 8];
                z2[0] = 0u; z2[1] = 0u; z2[2] = 0u; z2[3] = 0u;
            }
        }
        // stage2 B-frags straight from global (L2-broadcast), issued pre-barrier
        short8v bh0[3], bh1[3], bl0[3], bl1[3];
        #pragma unroll
        for (int nf = 0; nf < 3; ++nf) {
            bh0[nf] = *(const short8v*)(&s2wp[(nf * 16 + lr) * 72 + q * 8]);
            bh1[nf] = *(const short8v*)(&s2wp[(nf * 16 + lr) * 72 + 32 + q * 8]);
            bl0[nf] = *(const short8v*)(&s2wp[(48 + nf * 16 + lr) * 72 + q * 8]);
            bl1[nf] = *(const short8v*)(&s2wp[(48 + nf * 16 + lr) * 72 + 32 + q * 8]);
        }
        __syncthreads();
        short8v a0 = *(const short8v*)&lds[XB + (wv * 16 + lr) * 72 + q * 8];
        short8v a1 = *(const short8v*)&lds[XB + (wv * 16 + lr) * 72 + 32 + q * 8];
        f32x4 y[3];
        #pragma unroll
        for (int nf = 0; nf < 3; ++nf) {
            y[nf] = (f32x4){0.f, 0.f, 0.f, 0.f};
            y[nf] = __builtin_amdgcn_mfma_f32_16x16x32_bf16(a0, bh0[nf], y[nf], 0, 0, 0);
            y[nf] = __builtin_amdgcn_mfma_f32_16x16x32_bf16(a1, bh1[nf], y[nf], 0, 0, 0);
            y[nf] = __builtin_amdgcn_mfma_f32_16x16x32_bf16(a0, bl0[nf], y[nf], 0, 0, 0);
            y[nf] = __builtin_amdgcn_mfma_f32_16x16x32_bf16(a1, bl1[nf], y[nf], 0, 0, 0);
        }
        __syncthreads();
        // scatter y -> IMG4 interior (c 0..2; c=3 plane + halo stay zero).
        // Over-read window [4624,4628) lands in XB/IN2 head: feeds kw==3
        // slots whose conv1 weights are zero -> safe.
        #pragma unroll
        for (int nf = 0; nf < 3; ++nf)
            #pragma unroll
            for (int r = 0; r < 4; ++r) {
                int n2 = wv * 16 + q * 4 + r;
                int o  = nf * 16 + lr;
                int ir = o / 12, rm = o - ir * 12;
                int jc = rm / 3, c = rm - jc * 3;
                int hh = (n2 >> 3) * 4 + ir, ww = (n2 & 7) * 4 + jc;
                lds[IMG4 + ((hh + 1) * 34 + (ww + 1)) * 4 + c] = f2bu(y[nf][r]);
            }
    } else {
        if (t < 4) z32[2312 + t] = 0u;     // conv1 over-read window
        __syncthreads();
        for (int e = t; e < 3072; e += 256) {
            int hh = e / 96, rm = e - hh * 96;
            int ww = rm / 3, c = rm - ww * 3;
            lds[IMG4 + ((hh + 1) * 34 + (ww + 1)) * 4 + c] = f2bu(x[(size_t)b * 3072 + e]);
        }
    }
    __syncthreads();     // IMG4 complete; XB dead after this phase

    // ---- P2: conv1 via 32x32x16 MFMA -> IN2 (stride 36); zero IN2 halo ----
    for (int i = t; i < 1224; i += 256) {            // in2 halo: 68 cells x 18 dw
        int cell = i / 18, d = i - cell * 18;
        int h, w;
        if (cell < 18)      { h = 0;  w = cell; }
        else if (cell < 36) { h = 17; w = cell - 18; }
        else { int k = cell - 36; h = 1 + (k >> 1); w = (k & 1) * 17; }
        z32[2312 + (h * 18 + w) * 18 + d] = 0u;      // IN2/2 = 2312
    }
    {
        const float bias1 = c1b[oc32];
        #pragma unroll
        for (int chk = 0; chk < 4; ++chk) {          // chunk = 2 h-rows
            f32x16 acc0, acc1;
            #pragma unroll
            for (int i = 0; i < 16; ++i) { acc0[i] = 0.f; acc1[i] = 0.f; }
            #pragma unroll
            for (int s = 0; s < 3; ++s) {
                #pragma unroll
                for (int f = 0; f < 2; ++f) {
                    const int h = wv * 8 + chk * 2 + f;
                    const int a4 = ((h + s) * 34 + oc32 + hi * 2) * 4;
                    pack8 pk;
                    *(unsigned long long*)&pk.u[0] = *(const unsigned long long*)(&lds[IMG4 + a4]);
                    *(unsigned long long*)&pk.u[2] = *(const unsigned long long*)(&lds[IMG4 + a4 + 4]);
                    if (f == 0) acc0 = __builtin_amdgcn_mfma_f32_32x32x16_bf16(pk.v, wb1[s], acc0, 0, 0, 0);
                    else        acc1 = __builtin_amdgcn_mfma_f32_32x32x16_bf16(pk.v, wb1[s], acc1, 0, 0, 0);
                }
            }
            const int hq = wv * 4 + chk;
            #pragma unroll
            for (int g = 0; g < 4; ++g) {
                #pragma unroll
                for (int pp = 0; pp < 2; ++pp) {
                    const int i0 = 4 * g + 2 * pp;
                    float m0 = fmaxf(acc0[i0], acc0[i0 + 1]);
                    float m1 = fmaxf(acc1[i0], acc1[i0 + 1]);
                    float v = fmaxf(fmaxf(m0, m1) + bias1, 0.f);
                    const int wq = 4 * g + 2 * hi + pp;
                    lds[IN2 + ((hq + 1) * 18 + (wq + 1)) * 36 + oc32] = f2bu(v);
                }
            }
        }
    }
    __syncthreads();     // IN2 complete; IMG4 dead after this phase

    // ---- P3: conv2 two N=32 halves, pooled -> regs; IN3 writes deferred ----
    float poo[16];
    #pragma unroll
    for (int nh = 0; nh < 2; ++nh) {
        const u16* wb2 = w2p + (size_t)(nh * 32 + lr) * 296 + q * 8;
        f32x4 acc[4][2];
        #pragma unroll
        for (int m = 0; m < 4; ++m)
            #pragma unroll
            for (int n = 0; n < 2; ++n) acc[m][n] = (f32x4){0.f, 0.f, 0.f, 0.f};

        short8v bfr[3][2];
        #pragma unroll
        for (int n = 0; n < 2; ++n) {
            bfr[0][n] = *(const short8v*)(wb2 + n * 4736 + 0);
            bfr[1][n] = *(const short8v*)(wb2 + n * 4736 + 32);
        }
        #pragma unroll
        for (int s = 0; s < 9; ++s) {
            if (s + 2 < 9) {
                #pragma unroll
                for (int n = 0; n < 2; ++n)
                    bfr[(s + 2) % 3][n] = *(const short8v*)(wb2 + n * 4736 + (s + 2) * 32);
            }
            const int kh = s / 3, kw = s - kh * 3;
            short8v af[4];
            #pragma unroll
            for (int m = 0; m < 4; ++m)
                af[m] = *(const short8v*)(&lds[IN2 + ((wv * 4 + m + kh) * 18 + lr + kw) * 36 + q * 8]);
            __builtin_amdgcn_s_setprio(1);
            #pragma unroll
            for (int m = 0; m < 4; ++m)
                #pragma unroll
                for (int n = 0; n < 2; ++n)
                    acc[m][n] = __builtin_amdgcn_mfma_f32_16x16x32_bf16(af[m], bfr[s % 3][n], acc[m][n], 0, 0, 0);
            __builtin_amdgcn_s_setprio(0);
        }
        // pool -> +bias -> relu -> regs (write deferred)
        #pragma unroll
        for (int n = 0; n < 2; ++n) {
            float bias = c2b[nh * 32 + n * 16 + lr];
            #pragma unroll
            for (int mp = 0; mp < 2; ++mp) {
                #pragma unroll
                for (int p = 0; p < 2; ++p) {
                    float m0 = fmaxf(acc[2 * mp][n][2 * p], acc[2 * mp][n][2 * p + 1]);
                    float m1 = fmaxf(acc[2 * mp + 1][n][2 * p], acc[2 * mp + 1][n][2 * p + 1]);
                    poo[nh * 8 + n * 4 + mp * 2 + p] = fmaxf(fmaxf(m0, m1) + bias, 0.f);
                }
            }
        }
    }
    __syncthreads();     // all IN2 reads complete; IN2 dead -> IN3 may overlay

    // zero IN3 halo, then write interior from poo
    for (int i = t; i < 1152; i += 256) {            // in3 halo: 36 cells x 32 dw
        int cell = i >> 5, d = i & 31;
        int pos;
        if (cell < 10)      pos = cell;
        else if (cell < 20) pos = 90 + (cell - 10);
        else { int k = cell - 20; pos = (1 + (k >> 1)) * 10 + (k & 1) * 9; }
        z32[pos * 32 + d] = 0u;                      // IN3/2 = 0
    }
    #pragma unroll
    for (int nh = 0; nh < 2; ++nh)
        #pragma unroll
        for (int n = 0; n < 2; ++n)
            #pragma unroll
            for (int mp = 0; mp < 2; ++mp)
                #pragma unroll
                for (int p = 0; p < 2; ++p) {
                    int hq = wv * 2 + mp, wq = 2 * q + p;
                    int posW = (hq + 1) * 10 + (wq + 1);
                    int oc = nh * 32 + n * 16 + lr;
                    lds[IN3 + posW * 64 + (oc ^ ((posW & 7) << 3))] =
                        f2bu(poo[nh * 8 + n * 4 + mp * 2 + p]);
                }
    __syncthreads();     // IN3 complete

    // ---- P4: conv3: wave wv -> oc block wv*32; pooled out -> XF (f32 LDS) ----
    {
        const int ocb = wv * 32;
        const int hA = lr >> 3, wA = lr & 7;
        const u16* wb3 = w3p + (size_t)(ocb + lr) * 584 + q * 8;

        f32x4 acc3[4][2];
        #pragma unroll
        for (int m = 0; m < 4; ++m)
            #pragma unroll
            for (int n = 0; n < 2; ++n) acc3[m][n] = (f32x4){0.f, 0.f, 0.f, 0.f};

        short8v br[3][2];
        #pragma unroll
        for (int n = 0; n < 2; ++n) {
            br[0][n] = *(const short8v*)(wb3 + n * 9344 + 0);
            br[1][n] = *(const short8v*)(wb3 + n * 9344 + 32);
        }
        #pragma unroll
        for (int s = 0; s < 18; ++s) {
            if (s + 2 < 18) {
                const int off2 = ((s + 2) >> 1) * 64 + ((s + 2) & 1) * 32;
                #pragma unroll
                for (int n = 0; n < 2; ++n)
                    br[(s + 2) % 3][n] = *(const short8v*)(wb3 + n * 9344 + off2);
            }
            const int tap = s >> 1, half = s & 1;
            const int kh = tap / 3, kw = tap - kh * 3;
            short8v a3[4];
            #pragma unroll
            for (int m = 0; m < 4; ++m) {
                int posR = (m * 2 + hA + kh) * 10 + wA + kw;
                int sl = (half * 32 + q * 8) ^ ((posR & 7) << 3);
                a3[m] = *(const short8v*)(&lds[IN3 + posR * 64 + sl]);
            }
            __builtin_amdgcn_s_setprio(1);
            #pragma unroll
            for (int m = 0; m < 4; ++m)
                #pragma unroll
                for (int n = 0; n < 2; ++n)
                    acc3[m][n] = __builtin_amdgcn_mfma_f32_16x16x32_bf16(a3[m], br[s % 3][n], acc3[m][n], 0, 0, 0);
            __builtin_amdgcn_s_setprio(0);
        }
        float* xff = (float*)lds;   // f32 view; XF at dw 3200
        #pragma unroll
        for (int n = 0; n < 2; ++n) {
            float bias = c3b[ocb + n * 16 + lr];
            #pragma unroll
            for (int m = 0; m < 4; ++m) {
                #pragma unroll
                for (int p = 0; p < 2; ++p) {
                    float mm = fmaxf(acc3[m][n][2 * p], acc3[m][n][2 * p + 1]);
                    float v2 = fmaxf(mm, __shfl_xor(mm, 32));
                    float v = fmaxf(v2 + bias, 0.f);
                    if (lane < 32) {
                        int wq = (q & 1) * 2 + p;
                        // NCHW-flat k = oc*16 + h*4 + w ; h = m, w = wq
                        xff[3200 + (ocb + n * 16 + lr) * 16 + m * 4 + wq] = v;
                    }
                }
            }
        }
    }
    __syncthreads();     // XF complete

    // ---- P5: fc (2048->10) + log_softmax, in-WG (f32 features) ----
    {
        const float* xf = (const float*)lds + 3200;
        const float4 xa = *(const float4*)(xf + t * 8);
        const float4 xc = *(const float4*)(xf + t * 8 + 4);
        float part[10];
        #pragma unroll
        for (int o = 0; o < 10; ++o) {
            const float* wr = fw + (size_t)o * 2048 + t * 8;
            const float4 wa = ((const float4*)wr)[0];
            const float4 wb = ((const float4*)wr)[1];
            part[o] = xa.x * wa.x + xa.y * wa.y + xa.z * wa.z + xa.w * wa.w
                    + xc.x * wb.x + xc.y * wb.y + xc.z * wb.z + xc.w * wb.w;
        }
        #pragma unroll
        for (int o = 0; o < 10; ++o) {
            float s = part[o];
            #pragma unroll
            for (int d = 32; d > 0; d >>= 1) s += __shfl_xor(s, d);
            part[o] = s;
        }
        float* redf = (float*)lds + 5248;   // 40 floats
        if (lane == 0) {
            #pragma unroll
            for (int o = 0; o < 10; ++o) redf[wv * 10 + o] = part[o];
        }
        __syncthreads();
        if (wv == 0) {
            float lg = -1e30f;
            if (lane < 10)
                lg = redf[lane] + redf[10 + lane] + redf[20 + lane] + redf[30 + lane] + fb[lane];
            float mx = lg;
            #pragma unroll
            for (int d = 8; d > 0; d >>= 1) mx = fmaxf(mx, __shfl_xor(mx, d));
            float ex = (lane < 10) ? expf(lg - mx) : 0.f;
            float den = ex;
            #pragma unroll
            for (int d = 8; d > 0; d >>= 1) den += __shfl_xor(den, d);
            if (lane < 10)
                out[(size_t)b * 10 + lane] = lg - mx - logf(den);
        }
    }
}

extern "C" void kernel_launch(void* const* d_in, const int* in_sizes, int n_in,
                              void* d_out, int out_size, void* d_ws, size_t ws_size,
                              hipStream_t stream)
{
    const float* x    = (const float*)d_in[0];
    const float* Wlin = (const float*)d_in[1];
    const float* c1w  = (const float*)d_in[2];
    const float* c1b  = (const float*)d_in[3];
    const float* c2w  = (const float*)d_in[4];
    const float* c2b  = (const float*)d_in[5];
    const float* c3w  = (const float*)d_in[6];
    const float* c3b  = (const float*)d_in[7];
    const float* fw   = (const float*)d_in[8];
    const float* fb   = (const float*)d_in[9];
    const int* stage  = (const int*)d_in[10];
    float* out = (float*)d_out;

    const int B = in_sizes[0] / 3072;      // 8192

    // ws: weights only.
    char* ws = (char*)d_ws;
    u16* w1p  = (u16*)(ws);
    u16* s2wp = (u16*)(ws + 4608);
    u16* w2p  = (u16*)(ws + 18432);
    u16* w3p  = (u16*)(ws + 56320);

    k_repack<<<288, 256, 0, stream>>>(Wlin, c1w, c2w, c3w, w1p, s2wp, w2p, w3p);
    k_img   <<<B, 256, 0, stream>>>(x, s2wp, w1p, c1b, stage, w2p, c2b, w3p, c3b, fw, fb, out);
}